// Round 1
// baseline (286.209 us; speedup 1.0000x reference)
//
#include <hip/hip_runtime.h>
#include <math.h>

#define B_   8
#define T_   2048
#define C_   1024
#define HS_  64
#define MTOT (B_*T_)          // 16384 rows

// ---------------------------------------------------------------------------
// Kernel 1: QKV projection.  out = x @ W for W in {Wq,Wk,Wv} selected by
// blockIdx.y.  Classic tiled fp32 GEMM: 64x64 output tile, BK=64,
// 256 threads, each computing 4 rows x 4 cols.  LDS rows padded to 68 floats
// (272 B -> keeps float4 alignment, spreads banks).
// ---------------------------------------------------------------------------
__global__ __launch_bounds__(256) void proj_kernel(
    const float* __restrict__ x,
    const float* __restrict__ Wq,
    const float* __restrict__ Wk,
    const float* __restrict__ Wv,
    float* __restrict__ ws)
{
    __shared__ float xs[64][68];
    __shared__ float wt[64][68];

    const int tid = threadIdx.x;
    const int tx  = tid & 15;        // col group: cols 4*tx..4*tx+3
    const int ty  = tid >> 4;        // row group: rows ty + 16*i
    const int m0  = blockIdx.x * 64;
    const int mat = blockIdx.y;      // 0=q, 1=k, 2=v

    const float* __restrict__ W = (mat == 0) ? Wq : (mat == 1) ? Wk : Wv;
    float* __restrict__ out = ws + (size_t)mat * (size_t)MTOT * HS_;

    float4 acc[4];
#pragma unroll
    for (int i = 0; i < 4; ++i) acc[i] = make_float4(0.f, 0.f, 0.f, 0.f);

    for (int kc = 0; kc < C_ / 64; ++kc) {
#pragma unroll
        for (int l = 0; l < 4; ++l) {
            int flat = tid + l * 256;           // float4 index over 64x64 tile
            int row  = flat >> 4;
            int c4   = (flat & 15) * 4;
            *(float4*)&xs[row][c4] =
                *(const float4*)&x[(size_t)(m0 + row) * C_ + kc * 64 + c4];
            *(float4*)&wt[row][c4] =
                *(const float4*)&W[(size_t)(kc * 64 + row) * HS_ + c4];
        }
        __syncthreads();

#pragma unroll 4
        for (int k4 = 0; k4 < 16; ++k4) {
            float4 a4[4];
#pragma unroll
            for (int i = 0; i < 4; ++i)
                a4[i] = *(const float4*)&xs[ty + 16 * i][k4 * 4];
#pragma unroll
            for (int kk = 0; kk < 4; ++kk) {
                float4 b4 = *(const float4*)&wt[k4 * 4 + kk][tx * 4];
#pragma unroll
                for (int i = 0; i < 4; ++i) {
                    float a = ((const float*)&a4[i])[kk];   // kk is compile-time
                    acc[i].x = fmaf(a, b4.x, acc[i].x);
                    acc[i].y = fmaf(a, b4.y, acc[i].y);
                    acc[i].z = fmaf(a, b4.z, acc[i].z);
                    acc[i].w = fmaf(a, b4.w, acc[i].w);
                }
            }
        }
        __syncthreads();
    }

#pragma unroll
    for (int i = 0; i < 4; ++i)
        *(float4*)&out[(size_t)(m0 + ty + 16 * i) * HS_ + tx * 4] = acc[i];
}

// ---------------------------------------------------------------------------
// Kernel 2: causal flash attention, fp32.
// QTILE=32, KTILE=32.  Block handles qtile pair (bx, 63-bx) for one batch ->
// exactly 65 key-tiles per block (perfect causal load balance).
// Thread (r = tid>>3, s = tid&7): owns S cols c = ci*8+s and O dims 8s..8s+7.
// ---------------------------------------------------------------------------
__global__ __launch_bounds__(256) void attn_kernel(
    const float* __restrict__ qg,
    const float* __restrict__ kg,
    const float* __restrict__ vg,
    float* __restrict__ y)
{
    __shared__ float Qs[32][68];
    __shared__ float Ks[32][68];
    __shared__ float Vs[32][68];
    __shared__ float Ps[32][68];

    const int tid = threadIdx.x;
    const int r   = tid >> 3;   // 0..31 query row in tile
    const int s   = tid & 7;    // 0..7 segment
    const int b   = blockIdx.y;
    const float scale = 0.03125f;  // 1024^-0.5

    for (int pass = 0; pass < 2; ++pass) {
        const int qt = (pass == 0) ? (int)blockIdx.x : 63 - (int)blockIdx.x;
        const int q0 = qt * 32;

        __syncthreads();
        // load Q tile (pre-scaled)
#pragma unroll
        for (int l = 0; l < 2; ++l) {
            int flat = tid + l * 256;
            int row  = flat >> 4;
            int c4   = (flat & 15) * 4;
            float4 t = *(const float4*)&qg[((size_t)b * T_ + q0 + row) * HS_ + c4];
            t.x *= scale; t.y *= scale; t.z *= scale; t.w *= scale;
            *(float4*)&Qs[row][c4] = t;
        }

        float oacc[8];
#pragma unroll
        for (int j = 0; j < 8; ++j) oacc[j] = 0.f;
        float mrow = -INFINITY, lrow = 0.f;
        __syncthreads();

        for (int kt = 0; kt <= qt; ++kt) {
            const int k0 = kt * 32;
#pragma unroll
            for (int l = 0; l < 2; ++l) {
                int flat = tid + l * 256;
                int row  = flat >> 4;
                int c4   = (flat & 15) * 4;
                *(float4*)&Ks[row][c4] =
                    *(const float4*)&kg[((size_t)b * T_ + k0 + row) * HS_ + c4];
                *(float4*)&Vs[row][c4] =
                    *(const float4*)&vg[((size_t)b * T_ + k0 + row) * HS_ + c4];
            }
            __syncthreads();

            // S = Q @ K^T for this thread's 4 columns (c = ci*8+s)
            float sacc[4] = {0.f, 0.f, 0.f, 0.f};
#pragma unroll 4
            for (int d4 = 0; d4 < 16; ++d4) {
                float4 q4 = *(const float4*)&Qs[r][d4 * 4];
#pragma unroll
                for (int ci = 0; ci < 4; ++ci) {
                    float4 k4 = *(const float4*)&Ks[ci * 8 + s][d4 * 4];
                    sacc[ci] += q4.x * k4.x + q4.y * k4.y +
                                q4.z * k4.z + q4.w * k4.w;
                }
            }

            // causal mask
            const int qi = q0 + r;
#pragma unroll
            for (int ci = 0; ci < 4; ++ci)
                if (k0 + ci * 8 + s > qi) sacc[ci] = -INFINITY;

            // online softmax: row stats across the 8 lanes of this row
            float mloc = fmaxf(fmaxf(sacc[0], sacc[1]), fmaxf(sacc[2], sacc[3]));
            mloc = fmaxf(mloc, __shfl_xor(mloc, 1));
            mloc = fmaxf(mloc, __shfl_xor(mloc, 2));
            mloc = fmaxf(mloc, __shfl_xor(mloc, 4));
            float mnew = fmaxf(mrow, mloc);
            float corr = __expf(mrow - mnew);

            float p[4];
            float psum = 0.f;
#pragma unroll
            for (int ci = 0; ci < 4; ++ci) {
                p[ci] = __expf(sacc[ci] - mnew);
                psum += p[ci];
            }
            psum += __shfl_xor(psum, 1);
            psum += __shfl_xor(psum, 2);
            psum += __shfl_xor(psum, 4);

            lrow = lrow * corr + psum;
            mrow = mnew;
#pragma unroll
            for (int j = 0; j < 8; ++j) oacc[j] *= corr;

#pragma unroll
            for (int ci = 0; ci < 4; ++ci) Ps[r][ci * 8 + s] = p[ci];
            __syncthreads();

            // O += P @ V  (thread owns dims s*8..s*8+7)
#pragma unroll 8
            for (int c = 0; c < 32; ++c) {
                float pv  = Ps[r][c];
                float4 v0 = *(const float4*)&Vs[c][s * 8];
                float4 v1 = *(const float4*)&Vs[c][s * 8 + 4];
                oacc[0] = fmaf(pv, v0.x, oacc[0]);
                oacc[1] = fmaf(pv, v0.y, oacc[1]);
                oacc[2] = fmaf(pv, v0.z, oacc[2]);
                oacc[3] = fmaf(pv, v0.w, oacc[3]);
                oacc[4] = fmaf(pv, v1.x, oacc[4]);
                oacc[5] = fmaf(pv, v1.y, oacc[5]);
                oacc[6] = fmaf(pv, v1.z, oacc[6]);
                oacc[7] = fmaf(pv, v1.w, oacc[7]);
            }
            __syncthreads();
        }

        const float inv = 1.0f / lrow;
        float4 o0 = make_float4(oacc[0] * inv, oacc[1] * inv,
                                oacc[2] * inv, oacc[3] * inv);
        float4 o1 = make_float4(oacc[4] * inv, oacc[5] * inv,
                                oacc[6] * inv, oacc[7] * inv);
        float* yr = &y[((size_t)b * T_ + q0 + r) * HS_ + s * 8];
        *(float4*)&yr[0] = o0;
        *(float4*)&yr[4] = o1;
    }
}

extern "C" void kernel_launch(void* const* d_in, const int* in_sizes, int n_in,
                              void* d_out, int out_size, void* d_ws, size_t ws_size,
                              hipStream_t stream)
{
    const float* x  = (const float*)d_in[0];
    const float* Wq = (const float*)d_in[1];
    const float* Wk = (const float*)d_in[2];
    const float* Wv = (const float*)d_in[3];
    float* out = (float*)d_out;
    float* ws  = (float*)d_ws;

    float* q = ws;                              // [B,T,HS] fp32
    float* k = ws + (size_t)MTOT * HS_;         // [B,T,HS]
    float* v = ws + 2 * (size_t)MTOT * HS_;     // [B,T,HS]

    // QKV projection: 256 row-tiles x 3 matrices
    proj_kernel<<<dim3(MTOT / 64, 3), 256, 0, stream>>>(x, Wq, Wk, Wv, ws);

    // causal flash attention: 32 qtile-pairs x 8 batches
    attn_kernel<<<dim3(32, B_), 256, 0, stream>>>(q, k, v, out);
}

// Round 2
// 149.525 us; speedup vs baseline: 1.9141x; 1.9141x over previous
//
#include <hip/hip_runtime.h>
#include <hip/hip_bf16.h>
#include <math.h>

#define B_   8
#define T_   2048
#define C_   1024
#define HS_  64
#define MTOT (B_*T_)          // 16384 rows

typedef __attribute__((ext_vector_type(8))) short bf16x8;   // 8 bf16 = 4 VGPR
typedef __attribute__((ext_vector_type(4))) float f32x4;    // MFMA C/D

static __device__ __forceinline__ unsigned short f2bf(float f) {
    __hip_bfloat16 h = __float2bfloat16(f);
    return *reinterpret_cast<unsigned short*>(&h);
}

// ---------------------------------------------------------------------------
// Kernel 1: QKV projection (fp32 compute, validated round 0).
// New: emits bf16 outputs — q scaled by C^-0.5, k row-major [tok][hs],
// v TRANSPOSED per batch [hs][tok] (via LDS so global writes coalesce).
// ---------------------------------------------------------------------------
__global__ __launch_bounds__(256) void proj_kernel(
    const float* __restrict__ x,
    const float* __restrict__ Wq,
    const float* __restrict__ Wk,
    const float* __restrict__ Wv,
    unsigned short* __restrict__ qbf,
    unsigned short* __restrict__ kbf,
    unsigned short* __restrict__ vtbf)
{
    __shared__ float xs[64][68];
    __shared__ float wt[64][68];

    const int tid = threadIdx.x;
    const int tx  = tid & 15;        // col group: cols 4*tx..4*tx+3
    const int ty  = tid >> 4;        // row group: rows ty + 16*i
    const int m0  = blockIdx.x * 64;
    const int mat = blockIdx.y;      // 0=q, 1=k, 2=v

    const float* __restrict__ W = (mat == 0) ? Wq : (mat == 1) ? Wk : Wv;

    float4 acc[4];
#pragma unroll
    for (int i = 0; i < 4; ++i) acc[i] = make_float4(0.f, 0.f, 0.f, 0.f);

    for (int kc = 0; kc < C_ / 64; ++kc) {
#pragma unroll
        for (int l = 0; l < 4; ++l) {
            int flat = tid + l * 256;
            int row  = flat >> 4;
            int c4   = (flat & 15) * 4;
            *(float4*)&xs[row][c4] =
                *(const float4*)&x[(size_t)(m0 + row) * C_ + kc * 64 + c4];
            *(float4*)&wt[row][c4] =
                *(const float4*)&W[(size_t)(kc * 64 + row) * HS_ + c4];
        }
        __syncthreads();

#pragma unroll 4
        for (int k4 = 0; k4 < 16; ++k4) {
            float4 a4[4];
#pragma unroll
            for (int i = 0; i < 4; ++i)
                a4[i] = *(const float4*)&xs[ty + 16 * i][k4 * 4];
#pragma unroll
            for (int kk = 0; kk < 4; ++kk) {
                float4 b4 = *(const float4*)&wt[k4 * 4 + kk][tx * 4];
#pragma unroll
                for (int i = 0; i < 4; ++i) {
                    float a = ((const float*)&a4[i])[kk];
                    acc[i].x = fmaf(a, b4.x, acc[i].x);
                    acc[i].y = fmaf(a, b4.y, acc[i].y);
                    acc[i].z = fmaf(a, b4.z, acc[i].z);
                    acc[i].w = fmaf(a, b4.w, acc[i].w);
                }
            }
        }
        __syncthreads();
    }

    if (mat == 0) {
        const float s = 0.03125f;    // 1024^-0.5 folded into q
#pragma unroll
        for (int i = 0; i < 4; ++i) {
            ushort4 o;
            o.x = f2bf(acc[i].x * s); o.y = f2bf(acc[i].y * s);
            o.z = f2bf(acc[i].z * s); o.w = f2bf(acc[i].w * s);
            *(ushort4*)&qbf[(size_t)(m0 + ty + 16 * i) * HS_ + tx * 4] = o;
        }
    } else if (mat == 1) {
#pragma unroll
        for (int i = 0; i < 4; ++i) {
            ushort4 o;
            o.x = f2bf(acc[i].x); o.y = f2bf(acc[i].y);
            o.z = f2bf(acc[i].z); o.w = f2bf(acc[i].w);
            *(ushort4*)&kbf[(size_t)(m0 + ty + 16 * i) * HS_ + tx * 4] = o;
        }
    } else {
        // transpose 64 tokens x 64 hs through LDS, write vt[b][hs][tok] bf16
        __syncthreads();
#pragma unroll
        for (int i = 0; i < 4; ++i) {
            xs[ty + 16 * i][tx * 4 + 0] = acc[i].x;
            xs[ty + 16 * i][tx * 4 + 1] = acc[i].y;
            xs[ty + 16 * i][tx * 4 + 2] = acc[i].z;
            xs[ty + 16 * i][tx * 4 + 3] = acc[i].w;
        }
        __syncthreads();
        const int hs  = tid >> 2;
        const int seg = tid & 3;
        const int b   = m0 >> 11;
        const int t0  = (m0 & 2047) + seg * 16;
        size_t base = ((size_t)b * HS_ + hs) * (size_t)T_ + t0;
#pragma unroll
        for (int j = 0; j < 4; ++j) {
            ushort4 o;
            o.x = f2bf(xs[seg * 16 + j * 4 + 0][hs]);
            o.y = f2bf(xs[seg * 16 + j * 4 + 1][hs]);
            o.z = f2bf(xs[seg * 16 + j * 4 + 2][hs]);
            o.w = f2bf(xs[seg * 16 + j * 4 + 3][hs]);
            *(ushort4*)&vtbf[base + j * 4] = o;
        }
    }
}

// ---------------------------------------------------------------------------
// Kernel 2: causal flash attention, bf16 MFMA (16x16x32), swapped QK^T.
// Grid (32,8): block = pair (qbi, 63-qbi) of 32-query tiles, batch b.
// 4 waves: rg = wave&1 (query 16-group), h = wave>>1 (KV 32-key half).
// KV tile = 64 keys staged in LDS; partial (m,l,O) merged flash-style.
// Wave-private fragment conventions (consistent-sigma, see analysis):
//   S^T = K·Q^T: A-frag lane = K[ksub*16 + (l&15)][g*8 + j (+32*half)]
//                B-frag lane = Q[qq0 + (l&15)][g*8 + j (+32*half)] (prescaled)
//   C/D: col(query)=lane&15, row(key)=g*4+reg   [guide-verified]
//   PV:  A = P (lane-local from S^T), B = Vt[hs=l&15][h*32 + {g*4+j | 16+g*4+j}]
// ---------------------------------------------------------------------------
__global__ __launch_bounds__(256) void attn_kernel(
    const unsigned short* __restrict__ qbf,
    const unsigned short* __restrict__ kbf,
    const unsigned short* __restrict__ vtbf,
    float* __restrict__ y)
{
    __shared__ unsigned short Ks[64][72];   // [key][hs]  pad->144B rows
    __shared__ unsigned short Vs[64][72];   // [hs][key]

    const int tid  = threadIdx.x;
    const int lane = tid & 63;
    const int wv   = tid >> 6;      // 0..3
    const int rg   = wv & 1;        // query row-group
    const int h    = wv >> 1;       // KV half
    const int g    = lane >> 4;
    const int n15  = lane & 15;
    const int g4   = g * 4;
    const int b    = blockIdx.y;
    const size_t qkoff = (size_t)b * T_ * HS_;
    const size_t voff  = (size_t)b * HS_ * T_;

    for (int pass = 0; pass < 2; ++pass) {
        const int qbi  = pass ? (63 - (int)blockIdx.x) : (int)blockIdx.x;
        const int q0   = qbi * 32;
        const int qq0  = q0 + rg * 16;
        const int qrow = qq0 + n15;
        const int nkt  = (qbi >> 1) + 1;

        bf16x8 qf0 = *(const bf16x8*)&qbf[qkoff + (size_t)qrow * HS_ + g * 8];
        bf16x8 qf1 = *(const bf16x8*)&qbf[qkoff + (size_t)qrow * HS_ + g * 8 + 32];

        f32x4 o0 = {0.f,0.f,0.f,0.f}, o1 = o0, o2 = o0, o3 = o0;
        float mrow = -INFINITY, lrow = 0.f;

        for (int kt = 0; kt < nkt; ++kt) {
            const int k0 = kt * 64;
            __syncthreads();
            {
                const unsigned short* kg = &kbf[qkoff + (size_t)k0 * HS_];
                const unsigned short* vg = &vtbf[voff + k0];
                int c = tid;
#pragma unroll
                for (int l = 0; l < 2; ++l, c += 256) {
                    int row = c >> 3, off = (c & 7) * 8;
                    *(int4*)&Ks[row][off] = *(const int4*)&kg[row * HS_ + off];
                    *(int4*)&Vs[row][off] = *(const int4*)&vg[(size_t)row * T_ + off];
                }
            }
            __syncthreads();

            // ---- S^T = K . Q^T  (this wave: keys [k0+h*32, +32)) ----
            const int ks0 = h * 32;
            f32x4 st0 = {0.f,0.f,0.f,0.f}, st1 = st0;
            {
                bf16x8 ka;
                ka  = *(const bf16x8*)&Ks[ks0 + n15][g * 8];
                st0 = __builtin_amdgcn_mfma_f32_16x16x32_bf16(ka, qf0, st0, 0, 0, 0);
                ka  = *(const bf16x8*)&Ks[ks0 + n15][g * 8 + 32];
                st0 = __builtin_amdgcn_mfma_f32_16x16x32_bf16(ka, qf1, st0, 0, 0, 0);
                ka  = *(const bf16x8*)&Ks[ks0 + 16 + n15][g * 8];
                st1 = __builtin_amdgcn_mfma_f32_16x16x32_bf16(ka, qf0, st1, 0, 0, 0);
                ka  = *(const bf16x8*)&Ks[ks0 + 16 + n15][g * 8 + 32];
                st1 = __builtin_amdgcn_mfma_f32_16x16x32_bf16(ka, qf1, st1, 0, 0, 0);
            }

            // ---- causal mask: value (reg r) key = k0+h*32+(16*sub)+g4+r,
            //      query = qrow ----
            const int kb = k0 + h * 32 + g4;
#pragma unroll
            for (int r = 0; r < 4; ++r) {
                if (kb + r      > qrow) st0[r] = -INFINITY;
                if (kb + 16 + r > qrow) st1[r] = -INFINITY;
            }

            // ---- online softmax (per query = n15; reduce over lanes ^16,^32) ----
            float mloc = fmaxf(fmaxf(st0[0], st0[1]), fmaxf(st0[2], st0[3]));
            mloc = fmaxf(mloc, fmaxf(fmaxf(st1[0], st1[1]), fmaxf(st1[2], st1[3])));
            mloc = fmaxf(mloc, __shfl_xor(mloc, 16));
            mloc = fmaxf(mloc, __shfl_xor(mloc, 32));
            float mnew = fmaxf(mrow, mloc);
            float mb   = fmaxf(mnew, -1e30f);       // guard fully-masked half
            float corr = __expf(mrow - mb);         // mrow=-inf -> 0
            float p[8];
            float psum = 0.f;
#pragma unroll
            for (int r = 0; r < 4; ++r) {
                p[r]     = __expf(st0[r] - mb);
                p[4 + r] = __expf(st1[r] - mb);
                psum += p[r] + p[4 + r];
            }
            psum += __shfl_xor(psum, 16);
            psum += __shfl_xor(psum, 32);
            lrow = lrow * corr + psum;
            mrow = mnew;

            // rescale O (O rows live at query g4+r -> fetch corr from lane g4+r)
#pragma unroll
            for (int r = 0; r < 4; ++r) {
                float cr = __shfl(corr, g4 + r);
                o0[r] *= cr; o1[r] *= cr; o2[r] *= cr; o3[r] *= cr;
            }

            // ---- P -> bf16 A-frag (lane-local, sigma: j<4 -> g4+j, j>=4 -> 16+g4+j) ----
            bf16x8 pa;
#pragma unroll
            for (int r = 0; r < 4; ++r) {
                pa[r]     = (short)f2bf(p[r]);
                pa[4 + r] = (short)f2bf(p[4 + r]);
            }

            // ---- O += P . V  (B-frag from Vs with the same sigma) ----
            const int kvo = h * 32;
            {
                ushort4 lo, hi; bf16x8 vb;
#define PV_STEP(NT, ONT)                                                   \
                lo = *(const ushort4*)&Vs[(NT)*16 + n15][kvo + g4];        \
                hi = *(const ushort4*)&Vs[(NT)*16 + n15][kvo + 16 + g4];   \
                vb[0] = (short)lo.x; vb[1] = (short)lo.y;                  \
                vb[2] = (short)lo.z; vb[3] = (short)lo.w;                  \
                vb[4] = (short)hi.x; vb[5] = (short)hi.y;                  \
                vb[6] = (short)hi.z; vb[7] = (short)hi.w;                  \
                ONT = __builtin_amdgcn_mfma_f32_16x16x32_bf16(pa, vb, ONT, 0, 0, 0);
                PV_STEP(0, o0)
                PV_STEP(1, o1)
                PV_STEP(2, o2)
                PV_STEP(3, o3)
#undef PV_STEP
            }
        }

        // ---- merge the two KV-halves (flash combine) + write out ----
        __syncthreads();
        float* Obuf = (float*)&Ks[0][0];            // [2][16][68] f32 (8704B)
        float* Mbuf = (float*)&Vs[0][0];            // [2][16]
        float* Lbuf = Mbuf + 32;                    // [2][16]
        if (h == 1) {
            float* Ob = Obuf + rg * 16 * 68;
#pragma unroll
            for (int r = 0; r < 4; ++r) {
                Ob[(g4 + r) * 68 +  0 + n15] = o0[r];
                Ob[(g4 + r) * 68 + 16 + n15] = o1[r];
                Ob[(g4 + r) * 68 + 32 + n15] = o2[r];
                Ob[(g4 + r) * 68 + 48 + n15] = o3[r];
            }
            if (g == 0) {
                Mbuf[rg * 16 + n15] = mrow;
                Lbuf[rg * 16 + n15] = lrow;
            }
        }
        __syncthreads();
        if (h == 0) {
            float m1 = Mbuf[rg * 16 + n15];
            float l1 = Lbuf[rg * 16 + n15];
            float mm = fmaxf(mrow, m1);
            float f0 = __expf(mrow - mm);           // mrow finite for h0
            float f1 = __expf(m1 - mm);             // m1=-inf -> 0
            float lnew = lrow * f0 + l1 * f1;
            float s0 = f0 / lnew, s1 = f1 / lnew;
            float* Ob = Obuf + rg * 16 * 68;
#pragma unroll
            for (int r = 0; r < 4; ++r) {
                float s0r = __shfl(s0, g4 + r);
                float s1r = __shfl(s1, g4 + r);
                float* yr = &y[((size_t)b * T_ + qq0 + g4 + r) * HS_];
                yr[ 0 + n15] = o0[r] * s0r + Ob[(g4 + r) * 68 +  0 + n15] * s1r;
                yr[16 + n15] = o1[r] * s0r + Ob[(g4 + r) * 68 + 16 + n15] * s1r;
                yr[32 + n15] = o2[r] * s0r + Ob[(g4 + r) * 68 + 32 + n15] * s1r;
                yr[48 + n15] = o3[r] * s0r + Ob[(g4 + r) * 68 + 48 + n15] * s1r;
            }
        }
    }
}

extern "C" void kernel_launch(void* const* d_in, const int* in_sizes, int n_in,
                              void* d_out, int out_size, void* d_ws, size_t ws_size,
                              hipStream_t stream)
{
    const float* x  = (const float*)d_in[0];
    const float* Wq = (const float*)d_in[1];
    const float* Wk = (const float*)d_in[2];
    const float* Wv = (const float*)d_in[3];

    unsigned short* qbf  = (unsigned short*)d_ws;                 // [B,T,64] bf16 (prescaled)
    unsigned short* kbf  = qbf + (size_t)MTOT * HS_;              // [B,T,64] bf16
    unsigned short* vtbf = kbf + (size_t)MTOT * HS_;              // [B,64,T] bf16

    proj_kernel<<<dim3(MTOT / 64, 3), 256, 0, stream>>>(x, Wq, Wk, Wv, qbf, kbf, vtbf);
    attn_kernel<<<dim3(32, B_), 256, 0, stream>>>(qbf, kbf, vtbf, (float*)d_out);
}

// Round 3
// 90.652 us; speedup vs baseline: 3.1572x; 1.6494x over previous
//
#include <hip/hip_runtime.h>
#include <hip/hip_bf16.h>
#include <math.h>

#define B_   8
#define T_   2048
#define C_   1024
#define HS_  64
#define MTOT (B_*T_)          // 16384 rows

typedef __attribute__((ext_vector_type(8))) short bf16x8;           // MFMA A/B
typedef __attribute__((ext_vector_type(4))) float f32x4;            // MFMA C/D
typedef __attribute__((ext_vector_type(8))) unsigned short u16x8;   // 16B store

static __device__ __forceinline__ unsigned short f2bf(float f) {
    __hip_bfloat16 h = __float2bfloat16(f);
    return *reinterpret_cast<unsigned short*>(&h);
}

// ---------------------------------------------------------------------------
// Kernel 0: cast W -> bf16, TRANSPOSED + concatenated: Wt[n=192][k=1024],
// n = mat*64 + col.  Q section pre-scaled by C^-0.5 (attn expects prescaled q).
// ---------------------------------------------------------------------------
__global__ __launch_bounds__(256) void cast_w_kernel(
    const float* __restrict__ Wq, const float* __restrict__ Wk,
    const float* __restrict__ Wv, unsigned short* __restrict__ Wt)
{
    const int tid = threadIdx.x;
    const int col = tid & 63;
    const int kc  = tid >> 6;                     // 0..3
    const int mat = blockIdx.y;
    const int k0  = (blockIdx.x * 4 + kc) * 8;
    const float* __restrict__ W = (mat == 0) ? Wq : (mat == 1) ? Wk : Wv;
    const float s = (mat == 0) ? 0.03125f : 1.0f;

    u16x8 o;
#pragma unroll
    for (int i = 0; i < 8; ++i)
        o[i] = f2bf(W[(size_t)(k0 + i) * HS_ + col] * s);
    *(u16x8*)&Wt[(size_t)(mat * 64 + col) * C_ + k0] = o;
}

// ---------------------------------------------------------------------------
// Kernel 1: QKV projection via bf16 MFMA.  grid = (M/64, 3 mats) = 768 blocks.
// 64x64 output tile, BK=64, 4 waves in 2x2 (each 32x32 = 2x2 16x16-frags).
// x (fp32) converted to bf16 during A-staging.  Fragment convention identical
// to the validated attn kernel:
//   A-frag lane = A[m = l&15][k = (l>>4)*8 + j]   (b128 from row-major LDS)
//   B-frag lane = B[k = (l>>4)*8 + j][n = l&15]   (b128 from Wt[n][k] LDS)
//   D: row = (l>>4)*4 + reg, col = l&15
// Epilogue stages C through LDS (row-major for q/k, transposed for v) so all
// global stores are coalesced int4.
// ---------------------------------------------------------------------------
__global__ __launch_bounds__(256) void proj_gemm(
    const float* __restrict__ x, const unsigned short* __restrict__ Wt,
    unsigned short* __restrict__ qbf, unsigned short* __restrict__ kbf,
    unsigned short* __restrict__ vtbf)
{
    __shared__ unsigned short Als[64][72];   // A tile [row][k], 144B rows
    __shared__ unsigned short Bls[64][72];   // B tile [n][k]

    const int tid  = threadIdx.x;
    const int lane = tid & 63;
    const int wv   = tid >> 6;
    const int wr   = wv & 1;          // row half (32)
    const int wc   = wv >> 1;         // col half (32)
    const int g    = lane >> 4;
    const int n15  = lane & 15;
    const int g4   = g * 4;
    const int m0   = blockIdx.x * 64;
    const int mat  = blockIdx.y;      // 0=q 1=k 2=v

    // staging map: 4 threads per row, 16 elems each
    const int srow = tid >> 2;
    const int kseg = (tid & 3) * 16;
    const float* __restrict__ xrow =
        &x[(size_t)(m0 + srow) * C_ + kseg];
    const unsigned short* __restrict__ wrow =
        &Wt[(size_t)(mat * 64 + srow) * C_ + kseg];

    f32x4 acc[2][2];
#pragma unroll
    for (int i = 0; i < 2; ++i)
#pragma unroll
        for (int j = 0; j < 2; ++j) acc[i][j] = (f32x4){0.f, 0.f, 0.f, 0.f};

    for (int kc = 0; kc < C_ / 64; ++kc) {
        // ---- stage A (fp32 -> bf16) ----
        float4 a0 = *(const float4*)&xrow[kc * 64 + 0];
        float4 a1 = *(const float4*)&xrow[kc * 64 + 4];
        float4 a2 = *(const float4*)&xrow[kc * 64 + 8];
        float4 a3 = *(const float4*)&xrow[kc * 64 + 12];
        u16x8 v0, v1;
        v0[0]=f2bf(a0.x); v0[1]=f2bf(a0.y); v0[2]=f2bf(a0.z); v0[3]=f2bf(a0.w);
        v0[4]=f2bf(a1.x); v0[5]=f2bf(a1.y); v0[6]=f2bf(a1.z); v0[7]=f2bf(a1.w);
        v1[0]=f2bf(a2.x); v1[1]=f2bf(a2.y); v1[2]=f2bf(a2.z); v1[3]=f2bf(a2.w);
        v1[4]=f2bf(a3.x); v1[5]=f2bf(a3.y); v1[6]=f2bf(a3.z); v1[7]=f2bf(a3.w);
        *(u16x8*)&Als[srow][kseg]     = v0;
        *(u16x8*)&Als[srow][kseg + 8] = v1;
        // ---- stage B (already bf16) ----
        *(int4*)&Bls[srow][kseg]     = *(const int4*)&wrow[kc * 64];
        *(int4*)&Bls[srow][kseg + 8] = *(const int4*)&wrow[kc * 64 + 8];
        __syncthreads();

#pragma unroll
        for (int kk = 0; kk < 2; ++kk) {
            bf16x8 fa0 = *(const bf16x8*)&Als[wr * 32 + n15][kk * 32 + g * 8];
            bf16x8 fa1 = *(const bf16x8*)&Als[wr * 32 + 16 + n15][kk * 32 + g * 8];
            bf16x8 fb0 = *(const bf16x8*)&Bls[wc * 32 + n15][kk * 32 + g * 8];
            bf16x8 fb1 = *(const bf16x8*)&Bls[wc * 32 + 16 + n15][kk * 32 + g * 8];
            acc[0][0] = __builtin_amdgcn_mfma_f32_16x16x32_bf16(fa0, fb0, acc[0][0], 0, 0, 0);
            acc[0][1] = __builtin_amdgcn_mfma_f32_16x16x32_bf16(fa0, fb1, acc[0][1], 0, 0, 0);
            acc[1][0] = __builtin_amdgcn_mfma_f32_16x16x32_bf16(fa1, fb0, acc[1][0], 0, 0, 0);
            acc[1][1] = __builtin_amdgcn_mfma_f32_16x16x32_bf16(fa1, fb1, acc[1][1], 0, 0, 0);
        }
        __syncthreads();
    }

    // ---- epilogue through LDS for coalesced stores ----
    if (mat != 2) {
        // row-major: Als[row][col]
#pragma unroll
        for (int rf = 0; rf < 2; ++rf)
#pragma unroll
            for (int cf = 0; cf < 2; ++cf) {
                int row = wr * 32 + rf * 16 + g4;
                int col = wc * 32 + cf * 16 + n15;
#pragma unroll
                for (int r = 0; r < 4; ++r)
                    Als[row + r][col] = f2bf(acc[rf][cf][r]);
            }
        __syncthreads();
        unsigned short* __restrict__ dst = (mat == 0) ? qbf : kbf;
#pragma unroll
        for (int p = 0; p < 2; ++p) {
            int flat = tid + p * 256;
            int row  = flat >> 3;
            int seg  = (flat & 7) * 8;
            *(int4*)&dst[(size_t)(m0 + row) * HS_ + seg] =
                *(const int4*)&Als[row][seg];
        }
    } else {
        // transposed: Als[col][row] -> vt[b][hs][tok]
#pragma unroll
        for (int rf = 0; rf < 2; ++rf)
#pragma unroll
            for (int cf = 0; cf < 2; ++cf) {
                int row = wr * 32 + rf * 16 + g4;   // token (4 consecutive)
                int col = wc * 32 + cf * 16 + n15;  // hs
                ushort4 o;
                o.x = f2bf(acc[rf][cf][0]); o.y = f2bf(acc[rf][cf][1]);
                o.z = f2bf(acc[rf][cf][2]); o.w = f2bf(acc[rf][cf][3]);
                *(ushort4*)&Als[col][row] = o;
            }
        __syncthreads();
        const int b  = m0 >> 11;
        const int t0 = m0 & 2047;
        const int hs   = tid >> 2;
        const int tseg = (tid & 3) * 16;
        unsigned short* __restrict__ vdst =
            &vtbf[((size_t)b * HS_ + hs) * T_ + t0 + tseg];
        *(int4*)&vdst[0] = *(const int4*)&Als[hs][tseg];
        *(int4*)&vdst[8] = *(const int4*)&Als[hs][tseg + 8];
    }
}

// ---------------------------------------------------------------------------
// Kernel 2: causal flash attention, bf16 MFMA (validated round 1, unchanged).
// ---------------------------------------------------------------------------
__global__ __launch_bounds__(256) void attn_kernel(
    const unsigned short* __restrict__ qbf,
    const unsigned short* __restrict__ kbf,
    const unsigned short* __restrict__ vtbf,
    float* __restrict__ y)
{
    __shared__ unsigned short Ks[64][72];   // [key][hs]
    __shared__ unsigned short Vs[64][72];   // [hs][key]

    const int tid  = threadIdx.x;
    const int lane = tid & 63;
    const int wv   = tid >> 6;
    const int rg   = wv & 1;
    const int h    = wv >> 1;
    const int g    = lane >> 4;
    const int n15  = lane & 15;
    const int g4   = g * 4;
    const int b    = blockIdx.y;
    const size_t qkoff = (size_t)b * T_ * HS_;
    const size_t voff  = (size_t)b * HS_ * T_;

    for (int pass = 0; pass < 2; ++pass) {
        const int qbi  = pass ? (63 - (int)blockIdx.x) : (int)blockIdx.x;
        const int q0   = qbi * 32;
        const int qq0  = q0 + rg * 16;
        const int qrow = qq0 + n15;
        const int nkt  = (qbi >> 1) + 1;

        bf16x8 qf0 = *(const bf16x8*)&qbf[qkoff + (size_t)qrow * HS_ + g * 8];
        bf16x8 qf1 = *(const bf16x8*)&qbf[qkoff + (size_t)qrow * HS_ + g * 8 + 32];

        f32x4 o0 = {0.f,0.f,0.f,0.f}, o1 = o0, o2 = o0, o3 = o0;
        float mrow = -INFINITY, lrow = 0.f;

        for (int kt = 0; kt < nkt; ++kt) {
            const int k0 = kt * 64;
            __syncthreads();
            {
                const unsigned short* kg = &kbf[qkoff + (size_t)k0 * HS_];
                const unsigned short* vg = &vtbf[voff + k0];
                int c = tid;
#pragma unroll
                for (int l = 0; l < 2; ++l, c += 256) {
                    int row = c >> 3, off = (c & 7) * 8;
                    *(int4*)&Ks[row][off] = *(const int4*)&kg[row * HS_ + off];
                    *(int4*)&Vs[row][off] = *(const int4*)&vg[(size_t)row * T_ + off];
                }
            }
            __syncthreads();

            const int ks0 = h * 32;
            f32x4 st0 = {0.f,0.f,0.f,0.f}, st1 = st0;
            {
                bf16x8 ka;
                ka  = *(const bf16x8*)&Ks[ks0 + n15][g * 8];
                st0 = __builtin_amdgcn_mfma_f32_16x16x32_bf16(ka, qf0, st0, 0, 0, 0);
                ka  = *(const bf16x8*)&Ks[ks0 + n15][g * 8 + 32];
                st0 = __builtin_amdgcn_mfma_f32_16x16x32_bf16(ka, qf1, st0, 0, 0, 0);
                ka  = *(const bf16x8*)&Ks[ks0 + 16 + n15][g * 8];
                st1 = __builtin_amdgcn_mfma_f32_16x16x32_bf16(ka, qf0, st1, 0, 0, 0);
                ka  = *(const bf16x8*)&Ks[ks0 + 16 + n15][g * 8 + 32];
                st1 = __builtin_amdgcn_mfma_f32_16x16x32_bf16(ka, qf1, st1, 0, 0, 0);
            }

            const int kb = k0 + h * 32 + g4;
#pragma unroll
            for (int r = 0; r < 4; ++r) {
                if (kb + r      > qrow) st0[r] = -INFINITY;
                if (kb + 16 + r > qrow) st1[r] = -INFINITY;
            }

            float mloc = fmaxf(fmaxf(st0[0], st0[1]), fmaxf(st0[2], st0[3]));
            mloc = fmaxf(mloc, fmaxf(fmaxf(st1[0], st1[1]), fmaxf(st1[2], st1[3])));
            mloc = fmaxf(mloc, __shfl_xor(mloc, 16));
            mloc = fmaxf(mloc, __shfl_xor(mloc, 32));
            float mnew = fmaxf(mrow, mloc);
            float mb   = fmaxf(mnew, -1e30f);
            float corr = __expf(mrow - mb);
            float p[8];
            float psum = 0.f;
#pragma unroll
            for (int r = 0; r < 4; ++r) {
                p[r]     = __expf(st0[r] - mb);
                p[4 + r] = __expf(st1[r] - mb);
                psum += p[r] + p[4 + r];
            }
            psum += __shfl_xor(psum, 16);
            psum += __shfl_xor(psum, 32);
            lrow = lrow * corr + psum;
            mrow = mnew;

#pragma unroll
            for (int r = 0; r < 4; ++r) {
                float cr = __shfl(corr, g4 + r);
                o0[r] *= cr; o1[r] *= cr; o2[r] *= cr; o3[r] *= cr;
            }

            bf16x8 pa;
#pragma unroll
            for (int r = 0; r < 4; ++r) {
                pa[r]     = (short)f2bf(p[r]);
                pa[4 + r] = (short)f2bf(p[4 + r]);
            }

            const int kvo = h * 32;
            {
                ushort4 lo, hi; bf16x8 vb;
#define PV_STEP(NT, ONT)                                                   \
                lo = *(const ushort4*)&Vs[(NT)*16 + n15][kvo + g4];        \
                hi = *(const ushort4*)&Vs[(NT)*16 + n15][kvo + 16 + g4];   \
                vb[0] = (short)lo.x; vb[1] = (short)lo.y;                  \
                vb[2] = (short)lo.z; vb[3] = (short)lo.w;                  \
                vb[4] = (short)hi.x; vb[5] = (short)hi.y;                  \
                vb[6] = (short)hi.z; vb[7] = (short)hi.w;                  \
                ONT = __builtin_amdgcn_mfma_f32_16x16x32_bf16(pa, vb, ONT, 0, 0, 0);
                PV_STEP(0, o0)
                PV_STEP(1, o1)
                PV_STEP(2, o2)
                PV_STEP(3, o3)
#undef PV_STEP
            }
        }

        __syncthreads();
        float* Obuf = (float*)&Ks[0][0];
        float* Mbuf = (float*)&Vs[0][0];
        float* Lbuf = Mbuf + 32;
        if (h == 1) {
            float* Ob = Obuf + rg * 16 * 68;
#pragma unroll
            for (int r = 0; r < 4; ++r) {
                Ob[(g4 + r) * 68 +  0 + n15] = o0[r];
                Ob[(g4 + r) * 68 + 16 + n15] = o1[r];
                Ob[(g4 + r) * 68 + 32 + n15] = o2[r];
                Ob[(g4 + r) * 68 + 48 + n15] = o3[r];
            }
            if (g == 0) {
                Mbuf[rg * 16 + n15] = mrow;
                Lbuf[rg * 16 + n15] = lrow;
            }
        }
        __syncthreads();
        if (h == 0) {
            float m1 = Mbuf[rg * 16 + n15];
            float l1 = Lbuf[rg * 16 + n15];
            float mm = fmaxf(mrow, m1);
            float f0 = __expf(mrow - mm);
            float f1 = __expf(m1 - mm);
            float lnew = lrow * f0 + l1 * f1;
            float s0 = f0 / lnew, s1 = f1 / lnew;
            float* Ob = Obuf + rg * 16 * 68;
#pragma unroll
            for (int r = 0; r < 4; ++r) {
                float s0r = __shfl(s0, g4 + r);
                float s1r = __shfl(s1, g4 + r);
                float* yr = &y[((size_t)b * T_ + qq0 + g4 + r) * HS_];
                yr[ 0 + n15] = o0[r] * s0r + Ob[(g4 + r) * 68 +  0 + n15] * s1r;
                yr[16 + n15] = o1[r] * s0r + Ob[(g4 + r) * 68 + 16 + n15] * s1r;
                yr[32 + n15] = o2[r] * s0r + Ob[(g4 + r) * 68 + 32 + n15] * s1r;
                yr[48 + n15] = o3[r] * s0r + Ob[(g4 + r) * 68 + 48 + n15] * s1r;
            }
        }
    }
}

extern "C" void kernel_launch(void* const* d_in, const int* in_sizes, int n_in,
                              void* d_out, int out_size, void* d_ws, size_t ws_size,
                              hipStream_t stream)
{
    const float* x  = (const float*)d_in[0];
    const float* Wq = (const float*)d_in[1];
    const float* Wk = (const float*)d_in[2];
    const float* Wv = (const float*)d_in[3];

    unsigned short* qbf  = (unsigned short*)d_ws;                 // [B,T,64] bf16 (prescaled)
    unsigned short* kbf  = qbf + (size_t)MTOT * HS_;              // [B,T,64] bf16
    unsigned short* vtbf = kbf + (size_t)MTOT * HS_;              // [B,64,T] bf16
    unsigned short* Wt   = vtbf + (size_t)MTOT * HS_;             // [192][1024] bf16

    cast_w_kernel<<<dim3(32, 3), 256, 0, stream>>>(Wq, Wk, Wv, Wt);
    proj_gemm<<<dim3(MTOT / 64, 3), 256, 0, stream>>>(x, Wt, qbf, kbf, vtbf);
    attn_kernel<<<dim3(32, B_), 256, 0, stream>>>(qbf, kbf, vtbf, (float*)d_out);
}

// Round 4
// 63.073 us; speedup vs baseline: 4.5377x; 1.4373x over previous
//
#include <hip/hip_runtime.h>
#include <hip/hip_bf16.h>
#include <math.h>

#define B_   8
#define T_   2048
#define C_   1024
#define HS_  64
#define MTOT (B_*T_)          // 16384 rows

typedef __attribute__((ext_vector_type(8))) short bf16x8;           // MFMA A/B
typedef __attribute__((ext_vector_type(4))) float f32x4;            // MFMA C/D
typedef __attribute__((ext_vector_type(8))) unsigned short u16x8;   // 16B store

static __device__ __forceinline__ unsigned short f2bf(float f) {
    __hip_bfloat16 h = __float2bfloat16(f);
    return *reinterpret_cast<unsigned short*>(&h);
}

// ---------------------------------------------------------------------------
// Kernel 0: cast W -> bf16, TRANSPOSED + concatenated: Wt[n=192][k=1024].
// Q section pre-scaled by C^-0.5.
// ---------------------------------------------------------------------------
__global__ __launch_bounds__(256) void cast_w_kernel(
    const float* __restrict__ Wq, const float* __restrict__ Wk,
    const float* __restrict__ Wv, unsigned short* __restrict__ Wt)
{
    const int tid = threadIdx.x;
    const int col = tid & 63;
    const int kc  = tid >> 6;                     // 0..3
    const int mat = blockIdx.y;
    const int k0  = (blockIdx.x * 4 + kc) * 8;
    const float* __restrict__ W = (mat == 0) ? Wq : (mat == 1) ? Wk : Wv;
    const float s = (mat == 0) ? 0.03125f : 1.0f;

    u16x8 o;
#pragma unroll
    for (int i = 0; i < 8; ++i)
        o[i] = f2bf(W[(size_t)(k0 + i) * HS_ + col] * s);
    *(u16x8*)&Wt[(size_t)(mat * 64 + col) * C_ + k0] = o;
}

// ---------------------------------------------------------------------------
// Kernel 1: QKV projection via bf16 MFMA, double-buffered LDS (T14 pattern:
// issue next k-tile loads early, compute current, write regs->LDS late).
// Fragment convention validated rounds 1-2 (unchanged).
// ---------------------------------------------------------------------------
__global__ __launch_bounds__(256) void proj_gemm(
    const float* __restrict__ x, const unsigned short* __restrict__ Wt,
    unsigned short* __restrict__ qbf, unsigned short* __restrict__ kbf,
    unsigned short* __restrict__ vtbf)
{
    __shared__ unsigned short Als[2][64][72];   // A tile [row][k]
    __shared__ unsigned short Bls[2][64][72];   // B tile [n][k]

    const int tid  = threadIdx.x;
    const int lane = tid & 63;
    const int wv   = tid >> 6;
    const int wr   = wv & 1;          // row half (32)
    const int wc   = wv >> 1;         // col half (32)
    const int g    = lane >> 4;
    const int n15  = lane & 15;
    const int g4   = g * 4;
    const int m0   = blockIdx.x * 64;
    const int mat  = blockIdx.y;      // 0=q 1=k 2=v

    // staging map: 4 threads per row, 16 elems each
    const int srow = tid >> 2;
    const int kseg = (tid & 3) * 16;
    const float* __restrict__ xrow = &x[(size_t)(m0 + srow) * C_ + kseg];
    const unsigned short* __restrict__ wrow =
        &Wt[(size_t)(mat * 64 + srow) * C_ + kseg];

    f32x4 acc[2][2];
#pragma unroll
    for (int i = 0; i < 2; ++i)
#pragma unroll
        for (int j = 0; j < 2; ++j) acc[i][j] = (f32x4){0.f, 0.f, 0.f, 0.f};

    float4 a0, a1, a2, a3;
    int4   b0, b1;

#define PROJ_LOAD(KC)                                                   \
    do {                                                                \
        a0 = *(const float4*)&xrow[(KC) * 64 + 0];                      \
        a1 = *(const float4*)&xrow[(KC) * 64 + 4];                      \
        a2 = *(const float4*)&xrow[(KC) * 64 + 8];                      \
        a3 = *(const float4*)&xrow[(KC) * 64 + 12];                     \
        b0 = *(const int4*)&wrow[(KC) * 64];                            \
        b1 = *(const int4*)&wrow[(KC) * 64 + 8];                        \
    } while (0)

#define PROJ_WRITE(BUF)                                                 \
    do {                                                                \
        u16x8 v0, v1;                                                   \
        v0[0]=f2bf(a0.x); v0[1]=f2bf(a0.y); v0[2]=f2bf(a0.z); v0[3]=f2bf(a0.w); \
        v0[4]=f2bf(a1.x); v0[5]=f2bf(a1.y); v0[6]=f2bf(a1.z); v0[7]=f2bf(a1.w); \
        v1[0]=f2bf(a2.x); v1[1]=f2bf(a2.y); v1[2]=f2bf(a2.z); v1[3]=f2bf(a2.w); \
        v1[4]=f2bf(a3.x); v1[5]=f2bf(a3.y); v1[6]=f2bf(a3.z); v1[7]=f2bf(a3.w); \
        *(u16x8*)&Als[BUF][srow][kseg]     = v0;                        \
        *(u16x8*)&Als[BUF][srow][kseg + 8] = v1;                        \
        *(int4*)&Bls[BUF][srow][kseg]     = b0;                         \
        *(int4*)&Bls[BUF][srow][kseg + 8] = b1;                         \
    } while (0)

    // prologue: stage k-tile 0 into buffer 0
    PROJ_LOAD(0);
    PROJ_WRITE(0);
    __syncthreads();

    for (int kc = 0; kc < C_ / 64; ++kc) {
        const int cur = kc & 1;
        const int kn  = (kc + 1 < C_ / 64) ? kc + 1 : kc;   // clamped
        PROJ_LOAD(kn);                                      // issue early

#pragma unroll
        for (int kk = 0; kk < 2; ++kk) {
            bf16x8 fa0 = *(const bf16x8*)&Als[cur][wr * 32 + n15][kk * 32 + g * 8];
            bf16x8 fa1 = *(const bf16x8*)&Als[cur][wr * 32 + 16 + n15][kk * 32 + g * 8];
            bf16x8 fb0 = *(const bf16x8*)&Bls[cur][wc * 32 + n15][kk * 32 + g * 8];
            bf16x8 fb1 = *(const bf16x8*)&Bls[cur][wc * 32 + 16 + n15][kk * 32 + g * 8];
            acc[0][0] = __builtin_amdgcn_mfma_f32_16x16x32_bf16(fa0, fb0, acc[0][0], 0, 0, 0);
            acc[0][1] = __builtin_amdgcn_mfma_f32_16x16x32_bf16(fa0, fb1, acc[0][1], 0, 0, 0);
            acc[1][0] = __builtin_amdgcn_mfma_f32_16x16x32_bf16(fa1, fb0, acc[1][0], 0, 0, 0);
            acc[1][1] = __builtin_amdgcn_mfma_f32_16x16x32_bf16(fa1, fb1, acc[1][1], 0, 0, 0);
        }

        if (kc + 1 < C_ / 64) {
            __syncthreads();            // everyone done reading buf cur^1 (tile kc-1)
            PROJ_WRITE(cur ^ 1);        // write regs late (vmcnt waits land here)
            __syncthreads();            // tile kc+1 visible
        }
    }
#undef PROJ_LOAD
#undef PROJ_WRITE

    // ---- epilogue through LDS buffer 0 for coalesced stores ----
    if (mat != 2) {
#pragma unroll
        for (int rf = 0; rf < 2; ++rf)
#pragma unroll
            for (int cf = 0; cf < 2; ++cf) {
                int row = wr * 32 + rf * 16 + g4;
                int col = wc * 32 + cf * 16 + n15;
#pragma unroll
                for (int r = 0; r < 4; ++r)
                    Als[0][row + r][col] = f2bf(acc[rf][cf][r]);
            }
        __syncthreads();
        unsigned short* __restrict__ dst = (mat == 0) ? qbf : kbf;
#pragma unroll
        for (int p = 0; p < 2; ++p) {
            int flat = tid + p * 256;
            int row  = flat >> 3;
            int seg  = (flat & 7) * 8;
            *(int4*)&dst[(size_t)(m0 + row) * HS_ + seg] =
                *(const int4*)&Als[0][row][seg];
        }
    } else {
        // transposed: Als[0][col][row] -> vt[b][hs][tok]
#pragma unroll
        for (int rf = 0; rf < 2; ++rf)
#pragma unroll
            for (int cf = 0; cf < 2; ++cf) {
                int row = wr * 32 + rf * 16 + g4;   // token (4 consecutive)
                int col = wc * 32 + cf * 16 + n15;  // hs
                ushort4 o;
                o.x = f2bf(acc[rf][cf][0]); o.y = f2bf(acc[rf][cf][1]);
                o.z = f2bf(acc[rf][cf][2]); o.w = f2bf(acc[rf][cf][3]);
                *(ushort4*)&Als[0][col][row] = o;
            }
        __syncthreads();
        const int b  = m0 >> 11;
        const int t0 = m0 & 2047;
        const int hs   = tid >> 2;
        const int tseg = (tid & 3) * 16;
        unsigned short* __restrict__ vdst =
            &vtbf[((size_t)b * HS_ + hs) * T_ + t0 + tseg];
        *(int4*)&vdst[0] = *(const int4*)&Als[0][hs][tseg];
        *(int4*)&vdst[8] = *(const int4*)&Als[0][hs][tseg + 8];
    }
}

// ---------------------------------------------------------------------------
// Kernel 2: causal flash attention, bf16 MFMA, double-buffered K/V staging
// (T14: issue-early / write-late).  MFMA + softmax logic validated r1-r2,
// unchanged; merge scratch moved to a dedicated LDS region.
// ---------------------------------------------------------------------------
__global__ __launch_bounds__(256) void attn_kernel(
    const unsigned short* __restrict__ qbf,
    const unsigned short* __restrict__ kbf,
    const unsigned short* __restrict__ vtbf,
    float* __restrict__ y)
{
    __shared__ unsigned short Ks[2][64][72];   // [key][hs]
    __shared__ unsigned short Vs[2][64][72];   // [hs][key]
    __shared__ float MergeO[2 * 16 * 68];      // [rg][qrow 16][68]
    __shared__ float MergeML[64];              // m[2*16], l[2*16]

    const int tid  = threadIdx.x;
    const int lane = tid & 63;
    const int wv   = tid >> 6;
    const int rg   = wv & 1;
    const int h    = wv >> 1;
    const int g    = lane >> 4;
    const int n15  = lane & 15;
    const int g4   = g * 4;
    const int b    = blockIdx.y;
    const size_t qkoff = (size_t)b * T_ * HS_;
    const size_t voff  = (size_t)b * HS_ * T_;

    const int srow = tid >> 3;          // 0..31
    const int soff = (tid & 7) * 8;

    const unsigned short* __restrict__ kgb = &kbf[qkoff];
    const unsigned short* __restrict__ vgb = &vtbf[voff];

    for (int pass = 0; pass < 2; ++pass) {
        const int qbi  = pass ? (63 - (int)blockIdx.x) : (int)blockIdx.x;
        const int q0   = qbi * 32;
        const int qq0  = q0 + rg * 16;
        const int qrow = qq0 + n15;
        const int nkt  = (qbi >> 1) + 1;

        bf16x8 qf0 = *(const bf16x8*)&qbf[qkoff + (size_t)qrow * HS_ + g * 8];
        bf16x8 qf1 = *(const bf16x8*)&qbf[qkoff + (size_t)qrow * HS_ + g * 8 + 32];

        f32x4 o0 = {0.f,0.f,0.f,0.f}, o1 = o0, o2 = o0, o3 = o0;
        float mrow = -INFINITY, lrow = 0.f;

        int4 kr0, kr1, vr0, vr1;
        // prologue: stage tile 0 into buffer 0
        kr0 = *(const int4*)&kgb[(size_t)srow * HS_ + soff];
        kr1 = *(const int4*)&kgb[(size_t)(srow + 32) * HS_ + soff];
        vr0 = *(const int4*)&vgb[(size_t)srow * T_ + soff];
        vr1 = *(const int4*)&vgb[(size_t)(srow + 32) * T_ + soff];
        __syncthreads();                 // prior pass done reading buffers
        *(int4*)&Ks[0][srow][soff]      = kr0;
        *(int4*)&Ks[0][srow + 32][soff] = kr1;
        *(int4*)&Vs[0][srow][soff]      = vr0;
        *(int4*)&Vs[0][srow + 32][soff] = vr1;
        __syncthreads();

        for (int kt = 0; kt < nkt; ++kt) {
            const int cur = kt & 1;
            const int kn  = ((kt + 1 < nkt) ? kt + 1 : kt) * 64;   // clamped
            // issue next-tile loads early; latency hides under compute
            kr0 = *(const int4*)&kgb[(size_t)(kn + srow) * HS_ + soff];
            kr1 = *(const int4*)&kgb[(size_t)(kn + srow + 32) * HS_ + soff];
            vr0 = *(const int4*)&vgb[(size_t)srow * T_ + kn + soff];
            vr1 = *(const int4*)&vgb[(size_t)(srow + 32) * T_ + kn + soff];

            const int k0 = kt * 64;

            // ---- S^T = K . Q^T  (this wave: keys [k0+h*32, +32)) ----
            const int ks0 = h * 32;
            f32x4 st0 = {0.f,0.f,0.f,0.f}, st1 = st0;
            {
                bf16x8 ka;
                ka  = *(const bf16x8*)&Ks[cur][ks0 + n15][g * 8];
                st0 = __builtin_amdgcn_mfma_f32_16x16x32_bf16(ka, qf0, st0, 0, 0, 0);
                ka  = *(const bf16x8*)&Ks[cur][ks0 + n15][g * 8 + 32];
                st0 = __builtin_amdgcn_mfma_f32_16x16x32_bf16(ka, qf1, st0, 0, 0, 0);
                ka  = *(const bf16x8*)&Ks[cur][ks0 + 16 + n15][g * 8];
                st1 = __builtin_amdgcn_mfma_f32_16x16x32_bf16(ka, qf0, st1, 0, 0, 0);
                ka  = *(const bf16x8*)&Ks[cur][ks0 + 16 + n15][g * 8 + 32];
                st1 = __builtin_amdgcn_mfma_f32_16x16x32_bf16(ka, qf1, st1, 0, 0, 0);
            }

            const int kb = k0 + h * 32 + g4;
#pragma unroll
            for (int r = 0; r < 4; ++r) {
                if (kb + r      > qrow) st0[r] = -INFINITY;
                if (kb + 16 + r > qrow) st1[r] = -INFINITY;
            }

            float mloc = fmaxf(fmaxf(st0[0], st0[1]), fmaxf(st0[2], st0[3]));
            mloc = fmaxf(mloc, fmaxf(fmaxf(st1[0], st1[1]), fmaxf(st1[2], st1[3])));
            mloc = fmaxf(mloc, __shfl_xor(mloc, 16));
            mloc = fmaxf(mloc, __shfl_xor(mloc, 32));
            float mnew = fmaxf(mrow, mloc);
            float mb   = fmaxf(mnew, -1e30f);
            float corr = __expf(mrow - mb);
            float p[8];
            float psum = 0.f;
#pragma unroll
            for (int r = 0; r < 4; ++r) {
                p[r]     = __expf(st0[r] - mb);
                p[4 + r] = __expf(st1[r] - mb);
                psum += p[r] + p[4 + r];
            }
            psum += __shfl_xor(psum, 16);
            psum += __shfl_xor(psum, 32);
            lrow = lrow * corr + psum;
            mrow = mnew;

#pragma unroll
            for (int r = 0; r < 4; ++r) {
                float cr = __shfl(corr, g4 + r);
                o0[r] *= cr; o1[r] *= cr; o2[r] *= cr; o3[r] *= cr;
            }

            bf16x8 pa;
#pragma unroll
            for (int r = 0; r < 4; ++r) {
                pa[r]     = (short)f2bf(p[r]);
                pa[4 + r] = (short)f2bf(p[4 + r]);
            }

            const int kvo = h * 32;
            {
                ushort4 lo, hi; bf16x8 vb;
#define PV_STEP(NT, ONT)                                                     \
                lo = *(const ushort4*)&Vs[cur][(NT)*16 + n15][kvo + g4];     \
                hi = *(const ushort4*)&Vs[cur][(NT)*16 + n15][kvo + 16 + g4];\
                vb[0] = (short)lo.x; vb[1] = (short)lo.y;                    \
                vb[2] = (short)lo.z; vb[3] = (short)lo.w;                    \
                vb[4] = (short)hi.x; vb[5] = (short)hi.y;                    \
                vb[6] = (short)hi.z; vb[7] = (short)hi.w;                    \
                ONT = __builtin_amdgcn_mfma_f32_16x16x32_bf16(pa, vb, ONT, 0, 0, 0);
                PV_STEP(0, o0)
                PV_STEP(1, o1)
                PV_STEP(2, o2)
                PV_STEP(3, o3)
#undef PV_STEP
            }

            if (kt + 1 < nkt) {
                __syncthreads();                 // done reading buf cur^1
                const int nx = cur ^ 1;
                *(int4*)&Ks[nx][srow][soff]      = kr0;
                *(int4*)&Ks[nx][srow + 32][soff] = kr1;
                *(int4*)&Vs[nx][srow][soff]      = vr0;
                *(int4*)&Vs[nx][srow + 32][soff] = vr1;
                __syncthreads();                 // next tile visible
            }
        }

        // ---- merge the two KV-halves (flash combine) + write out ----
        __syncthreads();
        float* Obuf = MergeO;
        float* Mbuf = MergeML;
        float* Lbuf = MergeML + 32;
        if (h == 1) {
            float* Ob = Obuf + rg * 16 * 68;
#pragma unroll
            for (int r = 0; r < 4; ++r) {
                Ob[(g4 + r) * 68 +  0 + n15] = o0[r];
                Ob[(g4 + r) * 68 + 16 + n15] = o1[r];
                Ob[(g4 + r) * 68 + 32 + n15] = o2[r];
                Ob[(g4 + r) * 68 + 48 + n15] = o3[r];
            }
            if (g == 0) {
                Mbuf[rg * 16 + n15] = mrow;
                Lbuf[rg * 16 + n15] = lrow;
            }
        }
        __syncthreads();
        if (h == 0) {
            float m1 = Mbuf[rg * 16 + n15];
            float l1 = Lbuf[rg * 16 + n15];
            float mm = fmaxf(mrow, m1);
            float f0 = __expf(mrow - mm);
            float f1 = __expf(m1 - mm);
            float lnew = lrow * f0 + l1 * f1;
            float s0 = f0 / lnew, s1 = f1 / lnew;
            float* Ob = Obuf + rg * 16 * 68;
#pragma unroll
            for (int r = 0; r < 4; ++r) {
                float s0r = __shfl(s0, g4 + r);
                float s1r = __shfl(s1, g4 + r);
                float* yr = &y[((size_t)b * T_ + qq0 + g4 + r) * HS_];
                yr[ 0 + n15] = o0[r] * s0r + Ob[(g4 + r) * 68 +  0 + n15] * s1r;
                yr[16 + n15] = o1[r] * s0r + Ob[(g4 + r) * 68 + 16 + n15] * s1r;
                yr[32 + n15] = o2[r] * s0r + Ob[(g4 + r) * 68 + 32 + n15] * s1r;
                yr[48 + n15] = o3[r] * s0r + Ob[(g4 + r) * 68 + 48 + n15] * s1r;
            }
        }
    }
}

extern "C" void kernel_launch(void* const* d_in, const int* in_sizes, int n_in,
                              void* d_out, int out_size, void* d_ws, size_t ws_size,
                              hipStream_t stream)
{
    const float* x  = (const float*)d_in[0];
    const float* Wq = (const float*)d_in[1];
    const float* Wk = (const float*)d_in[2];
    const float* Wv = (const float*)d_in[3];

    unsigned short* qbf  = (unsigned short*)d_ws;                 // [B,T,64] bf16 (prescaled)
    unsigned short* kbf  = qbf + (size_t)MTOT * HS_;              // [B,T,64] bf16
    unsigned short* vtbf = kbf + (size_t)MTOT * HS_;              // [B,64,T] bf16
    unsigned short* Wt   = vtbf + (size_t)MTOT * HS_;             // [192][1024] bf16

    cast_w_kernel<<<dim3(32, 3), 256, 0, stream>>>(Wq, Wk, Wv, Wt);
    proj_gemm<<<dim3(MTOT / 64, 3), 256, 0, stream>>>(x, Wt, qbf, kbf, vtbf);
    attn_kernel<<<dim3(32, B_), 256, 0, stream>>>(qbf, kbf, vtbf, (float*)d_out);
}

// Round 5
// 50.820 us; speedup vs baseline: 5.6318x; 1.2411x over previous
//
#include <hip/hip_runtime.h>
#include <hip/hip_bf16.h>
#include <math.h>

#define B_   8
#define T_   2048
#define C_   1024
#define HS_  64
#define MTOT (B_*T_)          // 16384 rows

typedef __attribute__((ext_vector_type(8))) short bf16x8;           // MFMA A/B
typedef __attribute__((ext_vector_type(4))) float f32x4;            // MFMA C/D
typedef __attribute__((ext_vector_type(8))) unsigned short u16x8;   // 16B store

static __device__ __forceinline__ unsigned short f2bf(float f) {
    __hip_bfloat16 h = __float2bfloat16(f);
    return *reinterpret_cast<unsigned short*>(&h);
}

// ---------------------------------------------------------------------------
// Kernel 0: cast W -> bf16, TRANSPOSED + concatenated: Wt[n=192][k=1024].
// Q section pre-scaled by C^-0.5.  (validated r2-r3, unchanged)
// ---------------------------------------------------------------------------
__global__ __launch_bounds__(256) void cast_w_kernel(
    const float* __restrict__ Wq, const float* __restrict__ Wk,
    const float* __restrict__ Wv, unsigned short* __restrict__ Wt)
{
    const int tid = threadIdx.x;
    const int col = tid & 63;
    const int kc  = tid >> 6;                     // 0..3
    const int mat = blockIdx.y;
    const int k0  = (blockIdx.x * 4 + kc) * 8;
    const float* __restrict__ W = (mat == 0) ? Wq : (mat == 1) ? Wk : Wv;
    const float s = (mat == 0) ? 0.03125f : 1.0f;

    u16x8 o;
#pragma unroll
    for (int i = 0; i < 8; ++i)
        o[i] = f2bf(W[(size_t)(k0 + i) * HS_ + col] * s);
    *(u16x8*)&Wt[(size_t)(mat * 64 + col) * C_ + k0] = o;
}

// ---------------------------------------------------------------------------
// Kernel 1: QKV projection via bf16 MFMA, double-buffered (validated r3,
// unchanged).
// ---------------------------------------------------------------------------
__global__ __launch_bounds__(256) void proj_gemm(
    const float* __restrict__ x, const unsigned short* __restrict__ Wt,
    unsigned short* __restrict__ qbf, unsigned short* __restrict__ kbf,
    unsigned short* __restrict__ vtbf)
{
    __shared__ unsigned short Als[2][64][72];   // A tile [row][k]
    __shared__ unsigned short Bls[2][64][72];   // B tile [n][k]

    const int tid  = threadIdx.x;
    const int lane = tid & 63;
    const int wv   = tid >> 6;
    const int wr   = wv & 1;          // row half (32)
    const int wc   = wv >> 1;         // col half (32)
    const int g    = lane >> 4;
    const int n15  = lane & 15;
    const int g4   = g * 4;
    const int m0   = blockIdx.x * 64;
    const int mat  = blockIdx.y;      // 0=q 1=k 2=v

    const int srow = tid >> 2;
    const int kseg = (tid & 3) * 16;
    const float* __restrict__ xrow = &x[(size_t)(m0 + srow) * C_ + kseg];
    const unsigned short* __restrict__ wrow =
        &Wt[(size_t)(mat * 64 + srow) * C_ + kseg];

    f32x4 acc[2][2];
#pragma unroll
    for (int i = 0; i < 2; ++i)
#pragma unroll
        for (int j = 0; j < 2; ++j) acc[i][j] = (f32x4){0.f, 0.f, 0.f, 0.f};

    float4 a0, a1, a2, a3;
    int4   b0, b1;

#define PROJ_LOAD(KC)                                                   \
    do {                                                                \
        a0 = *(const float4*)&xrow[(KC) * 64 + 0];                      \
        a1 = *(const float4*)&xrow[(KC) * 64 + 4];                      \
        a2 = *(const float4*)&xrow[(KC) * 64 + 8];                      \
        a3 = *(const float4*)&xrow[(KC) * 64 + 12];                     \
        b0 = *(const int4*)&wrow[(KC) * 64];                            \
        b1 = *(const int4*)&wrow[(KC) * 64 + 8];                        \
    } while (0)

#define PROJ_WRITE(BUF)                                                 \
    do {                                                                \
        u16x8 v0, v1;                                                   \
        v0[0]=f2bf(a0.x); v0[1]=f2bf(a0.y); v0[2]=f2bf(a0.z); v0[3]=f2bf(a0.w); \
        v0[4]=f2bf(a1.x); v0[5]=f2bf(a1.y); v0[6]=f2bf(a1.z); v0[7]=f2bf(a1.w); \
        v1[0]=f2bf(a2.x); v1[1]=f2bf(a2.y); v1[2]=f2bf(a2.z); v1[3]=f2bf(a2.w); \
        v1[4]=f2bf(a3.x); v1[5]=f2bf(a3.y); v1[6]=f2bf(a3.z); v1[7]=f2bf(a3.w); \
        *(u16x8*)&Als[BUF][srow][kseg]     = v0;                        \
        *(u16x8*)&Als[BUF][srow][kseg + 8] = v1;                        \
        *(int4*)&Bls[BUF][srow][kseg]     = b0;                         \
        *(int4*)&Bls[BUF][srow][kseg + 8] = b1;                         \
    } while (0)

    PROJ_LOAD(0);
    PROJ_WRITE(0);
    __syncthreads();

    for (int kc = 0; kc < C_ / 64; ++kc) {
        const int cur = kc & 1;
        const int kn  = (kc + 1 < C_ / 64) ? kc + 1 : kc;   // clamped
        PROJ_LOAD(kn);                                      // issue early

#pragma unroll
        for (int kk = 0; kk < 2; ++kk) {
            bf16x8 fa0 = *(const bf16x8*)&Als[cur][wr * 32 + n15][kk * 32 + g * 8];
            bf16x8 fa1 = *(const bf16x8*)&Als[cur][wr * 32 + 16 + n15][kk * 32 + g * 8];
            bf16x8 fb0 = *(const bf16x8*)&Bls[cur][wc * 32 + n15][kk * 32 + g * 8];
            bf16x8 fb1 = *(const bf16x8*)&Bls[cur][wc * 32 + 16 + n15][kk * 32 + g * 8];
            acc[0][0] = __builtin_amdgcn_mfma_f32_16x16x32_bf16(fa0, fb0, acc[0][0], 0, 0, 0);
            acc[0][1] = __builtin_amdgcn_mfma_f32_16x16x32_bf16(fa0, fb1, acc[0][1], 0, 0, 0);
            acc[1][0] = __builtin_amdgcn_mfma_f32_16x16x32_bf16(fa1, fb0, acc[1][0], 0, 0, 0);
            acc[1][1] = __builtin_amdgcn_mfma_f32_16x16x32_bf16(fa1, fb1, acc[1][1], 0, 0, 0);
        }

        if (kc + 1 < C_ / 64) {
            __syncthreads();
            PROJ_WRITE(cur ^ 1);
            __syncthreads();
        }
    }
#undef PROJ_LOAD
#undef PROJ_WRITE

    if (mat != 2) {
#pragma unroll
        for (int rf = 0; rf < 2; ++rf)
#pragma unroll
            for (int cf = 0; cf < 2; ++cf) {
                int row = wr * 32 + rf * 16 + g4;
                int col = wc * 32 + cf * 16 + n15;
#pragma unroll
                for (int r = 0; r < 4; ++r)
                    Als[0][row + r][col] = f2bf(acc[rf][cf][r]);
            }
        __syncthreads();
        unsigned short* __restrict__ dst = (mat == 0) ? qbf : kbf;
#pragma unroll
        for (int p = 0; p < 2; ++p) {
            int flat = tid + p * 256;
            int row  = flat >> 3;
            int seg  = (flat & 7) * 8;
            *(int4*)&dst[(size_t)(m0 + row) * HS_ + seg] =
                *(const int4*)&Als[0][row][seg];
        }
    } else {
#pragma unroll
        for (int rf = 0; rf < 2; ++rf)
#pragma unroll
            for (int cf = 0; cf < 2; ++cf) {
                int row = wr * 32 + rf * 16 + g4;   // token
                int col = wc * 32 + cf * 16 + n15;  // hs
                ushort4 o;
                o.x = f2bf(acc[rf][cf][0]); o.y = f2bf(acc[rf][cf][1]);
                o.z = f2bf(acc[rf][cf][2]); o.w = f2bf(acc[rf][cf][3]);
                *(ushort4*)&Als[0][col][row] = o;
            }
        __syncthreads();
        const int b  = m0 >> 11;
        const int t0 = m0 & 2047;
        const int hs   = tid >> 2;
        const int tseg = (tid & 3) * 16;
        unsigned short* __restrict__ vdst =
            &vtbf[((size_t)b * HS_ + hs) * T_ + t0 + tseg];
        *(int4*)&vdst[0] = *(const int4*)&Als[0][hs][tseg];
        *(int4*)&vdst[8] = *(const int4*)&Als[0][hs][tseg + 8];
    }
}

// ---------------------------------------------------------------------------
// Kernel 2: causal flash attention, bf16 MFMA.  NEW: 8 waves/block (512 thr,
// 2 waves/SIMD), tile-parity split-K: waves (rg, h, tp); tp-group computes
// tiles kt ≡ tp (mod 2) from its own LDS buffer -> 1 barrier per tile and
// cross-wave latency hiding.  4-way (h,tp) merge in reused LDS at pass end.
// MFMA/softmax/mask math identical to validated r1-r3.
// ---------------------------------------------------------------------------
__global__ __launch_bounds__(512) void attn_kernel(
    const unsigned short* __restrict__ qbf,
    const unsigned short* __restrict__ kbf,
    const unsigned short* __restrict__ vtbf,
    float* __restrict__ y)
{
    __shared__ unsigned short KVs[4][64][72];   // [0..1]=K bufs, [2..3]=V bufs

    const int tid  = threadIdx.x;
    const int lane = tid & 63;
    const int wv   = tid >> 6;        // 0..7
    const int rg   = wv & 1;          // query 16-group
    const int h    = (wv >> 1) & 1;   // KV 32-half within tile
    const int tp   = wv >> 2;         // tile parity group
    const int g    = lane >> 4;
    const int n15  = lane & 15;
    const int g4   = g * 4;
    const int b    = blockIdx.y;
    const size_t qkoff = (size_t)b * T_ * HS_;
    const size_t voff  = (size_t)b * HS_ * T_;

    const int sgrp = tid >> 8;        // staging group == its waves' tp
    const int st   = tid & 255;
    const int srow = st >> 3;         // 0..31
    const int soff = (st & 7) * 8;

    const unsigned short* __restrict__ kgb = &kbf[qkoff];
    const unsigned short* __restrict__ vgb = &vtbf[voff];

    for (int pass = 0; pass < 2; ++pass) {
        const int qbi  = pass ? (63 - (int)blockIdx.x) : (int)blockIdx.x;
        const int q0   = qbi * 32;
        const int qq0  = q0 + rg * 16;
        const int qrow = qq0 + n15;
        const int nkt  = (qbi >> 1) + 1;

        bf16x8 qf0 = *(const bf16x8*)&qbf[qkoff + (size_t)qrow * HS_ + g * 8];
        bf16x8 qf1 = *(const bf16x8*)&qbf[qkoff + (size_t)qrow * HS_ + g * 8 + 32];

        f32x4 o0 = {0.f,0.f,0.f,0.f}, o1 = o0, o2 = o0, o3 = o0;
        float mrow = -INFINITY, lrow = 0.f;

        int4 kr0, kr1, vr0, vr1;
        // prologue: group sgrp stages tile sgrp (clamped) into buffer sgrp
        {
            int tix = (sgrp < nkt) ? sgrp : nkt - 1;
            kr0 = *(const int4*)&kgb[(size_t)(tix * 64 + srow) * HS_ + soff];
            kr1 = *(const int4*)&kgb[(size_t)(tix * 64 + srow + 32) * HS_ + soff];
            vr0 = *(const int4*)&vgb[(size_t)srow * T_ + tix * 64 + soff];
            vr1 = *(const int4*)&vgb[(size_t)(srow + 32) * T_ + tix * 64 + soff];
        }
        __syncthreads();                 // prior pass done with LDS
        *(int4*)&KVs[sgrp][srow][soff]          = kr0;
        *(int4*)&KVs[sgrp][srow + 32][soff]     = kr1;
        *(int4*)&KVs[2 + sgrp][srow][soff]      = vr0;
        *(int4*)&KVs[2 + sgrp][srow + 32][soff] = vr1;
        __syncthreads();

        const int J = (nkt + 1) >> 1;
        for (int j = 0; j < J; ++j) {
            const int kt = 2 * j + tp;                 // my compute tile
            {
                int tix = 2 * j + sgrp + 2;            // my group's next tile
                if (tix > nkt - 1) tix = nkt - 1;      // clamped
                kr0 = *(const int4*)&kgb[(size_t)(tix * 64 + srow) * HS_ + soff];
                kr1 = *(const int4*)&kgb[(size_t)(tix * 64 + srow + 32) * HS_ + soff];
                vr0 = *(const int4*)&vgb[(size_t)srow * T_ + tix * 64 + soff];
                vr1 = *(const int4*)&vgb[(size_t)(srow + 32) * T_ + tix * 64 + soff];
            }

            if (kt < nkt) {
                const int k0  = kt * 64;
                const int ks0 = h * 32;
                f32x4 st0 = {0.f,0.f,0.f,0.f}, st1 = st0;
                {
                    bf16x8 ka;
                    ka  = *(const bf16x8*)&KVs[tp][ks0 + n15][g * 8];
                    st0 = __builtin_amdgcn_mfma_f32_16x16x32_bf16(ka, qf0, st0, 0, 0, 0);
                    ka  = *(const bf16x8*)&KVs[tp][ks0 + n15][g * 8 + 32];
                    st0 = __builtin_amdgcn_mfma_f32_16x16x32_bf16(ka, qf1, st0, 0, 0, 0);
                    ka  = *(const bf16x8*)&KVs[tp][ks0 + 16 + n15][g * 8];
                    st1 = __builtin_amdgcn_mfma_f32_16x16x32_bf16(ka, qf0, st1, 0, 0, 0);
                    ka  = *(const bf16x8*)&KVs[tp][ks0 + 16 + n15][g * 8 + 32];
                    st1 = __builtin_amdgcn_mfma_f32_16x16x32_bf16(ka, qf1, st1, 0, 0, 0);
                }

                const int kb = k0 + h * 32 + g4;
#pragma unroll
                for (int r = 0; r < 4; ++r) {
                    if (kb + r      > qrow) st0[r] = -INFINITY;
                    if (kb + 16 + r > qrow) st1[r] = -INFINITY;
                }

                float mloc = fmaxf(fmaxf(st0[0], st0[1]), fmaxf(st0[2], st0[3]));
                mloc = fmaxf(mloc, fmaxf(fmaxf(st1[0], st1[1]), fmaxf(st1[2], st1[3])));
                mloc = fmaxf(mloc, __shfl_xor(mloc, 16));
                mloc = fmaxf(mloc, __shfl_xor(mloc, 32));
                float mnew = fmaxf(mrow, mloc);
                float mb   = fmaxf(mnew, -1e30f);
                float corr = __expf(mrow - mb);
                float p[8];
                float psum = 0.f;
#pragma unroll
                for (int r = 0; r < 4; ++r) {
                    p[r]     = __expf(st0[r] - mb);
                    p[4 + r] = __expf(st1[r] - mb);
                    psum += p[r] + p[4 + r];
                }
                psum += __shfl_xor(psum, 16);
                psum += __shfl_xor(psum, 32);
                lrow = lrow * corr + psum;
                mrow = mnew;

#pragma unroll
                for (int r = 0; r < 4; ++r) {
                    float cr = __shfl(corr, g4 + r);
                    o0[r] *= cr; o1[r] *= cr; o2[r] *= cr; o3[r] *= cr;
                }

                bf16x8 pa;
#pragma unroll
                for (int r = 0; r < 4; ++r) {
                    pa[r]     = (short)f2bf(p[r]);
                    pa[4 + r] = (short)f2bf(p[4 + r]);
                }

                const int kvo = h * 32;
                {
                    ushort4 lo, hi; bf16x8 vb;
#define PV_STEP(NT, ONT)                                                        \
                    lo = *(const ushort4*)&KVs[2 + tp][(NT)*16 + n15][kvo + g4];\
                    hi = *(const ushort4*)&KVs[2 + tp][(NT)*16 + n15][kvo + 16 + g4];\
                    vb[0] = (short)lo.x; vb[1] = (short)lo.y;                   \
                    vb[2] = (short)lo.z; vb[3] = (short)lo.w;                   \
                    vb[4] = (short)hi.x; vb[5] = (short)hi.y;                   \
                    vb[6] = (short)hi.z; vb[7] = (short)hi.w;                   \
                    ONT = __builtin_amdgcn_mfma_f32_16x16x32_bf16(pa, vb, ONT, 0, 0, 0);
                    PV_STEP(0, o0)
                    PV_STEP(1, o1)
                    PV_STEP(2, o2)
                    PV_STEP(3, o3)
#undef PV_STEP
                }
            }

            if (j + 1 < J) {
                __syncthreads();                 // all readers done with both bufs
                *(int4*)&KVs[sgrp][srow][soff]          = kr0;
                *(int4*)&KVs[sgrp][srow + 32][soff]     = kr1;
                *(int4*)&KVs[2 + sgrp][srow][soff]      = vr0;
                *(int4*)&KVs[2 + sgrp][srow + 32][soff] = vr1;
                __syncthreads();                 // next tiles visible
            }
        }

        // ---- 4-way merge (partials pid = tp*2+h) in reused LDS ----
        __syncthreads();                          // all compute done
        float* FS = (float*)&KVs[0][0][0];        // 9216 floats scratch
        const int pid = (tp << 1) | h;
        if (pid != 0) {
            float* Ob = FS + (pid - 1) * 2176 + rg * 1088;
#pragma unroll
            for (int r = 0; r < 4; ++r) {
                Ob[(g4 + r) * 68 +  0 + n15] = o0[r];
                Ob[(g4 + r) * 68 + 16 + n15] = o1[r];
                Ob[(g4 + r) * 68 + 32 + n15] = o2[r];
                Ob[(g4 + r) * 68 + 48 + n15] = o3[r];
            }
            if (g == 0) {
                FS[6528 + (pid - 1) * 32 + rg * 16 + n15] = mrow;
                FS[6624 + (pid - 1) * 32 + rg * 16 + n15] = lrow;
            }
        }
        __syncthreads();
        if (pid == 0) {
            float m1 = FS[6528 +  0 + rg * 16 + n15];
            float m2 = FS[6528 + 32 + rg * 16 + n15];
            float m3 = FS[6528 + 64 + rg * 16 + n15];
            float l1 = FS[6624 +  0 + rg * 16 + n15];
            float l2 = FS[6624 + 32 + rg * 16 + n15];
            float l3 = FS[6624 + 64 + rg * 16 + n15];
            float mm = fmaxf(fmaxf(mrow, m1), fmaxf(m2, m3));   // finite: pid0 covers tile0/keys<=31
            float f0 = __expf(mrow - mm);
            float f1 = __expf(m1 - mm);
            float f2 = __expf(m2 - mm);
            float f3 = __expf(m3 - mm);
            float invl = 1.0f / (lrow * f0 + l1 * f1 + l2 * f2 + l3 * f3);
            const float* O1s = FS;
            const float* O2s = FS + 2176;
            const float* O3s = FS + 4352;
#pragma unroll
            for (int r = 0; r < 4; ++r) {
                float fr0 = __shfl(f0, g4 + r);
                float fr1 = __shfl(f1, g4 + r);
                float fr2 = __shfl(f2, g4 + r);
                float fr3 = __shfl(f3, g4 + r);
                float ir  = __shfl(invl, g4 + r);
                const int base = rg * 1088 + (g4 + r) * 68 + n15;
                float* yr = &y[((size_t)b * T_ + qq0 + g4 + r) * HS_];
                yr[ 0 + n15] = (o0[r] * fr0 + O1s[base]      * fr1 +
                                O2s[base]      * fr2 + O3s[base]      * fr3) * ir;
                yr[16 + n15] = (o1[r] * fr0 + O1s[base + 16] * fr1 +
                                O2s[base + 16] * fr2 + O3s[base + 16] * fr3) * ir;
                yr[32 + n15] = (o2[r] * fr0 + O1s[base + 32] * fr1 +
                                O2s[base + 32] * fr2 + O3s[base + 32] * fr3) * ir;
                yr[48 + n15] = (o3[r] * fr0 + O1s[base + 48] * fr1 +
                                O2s[base + 48] * fr2 + O3s[base + 48] * fr3) * ir;
            }
        }
    }
}

extern "C" void kernel_launch(void* const* d_in, const int* in_sizes, int n_in,
                              void* d_out, int out_size, void* d_ws, size_t ws_size,
                              hipStream_t stream)
{
    const float* x  = (const float*)d_in[0];
    const float* Wq = (const float*)d_in[1];
    const float* Wk = (const float*)d_in[2];
    const float* Wv = (const float*)d_in[3];

    unsigned short* qbf  = (unsigned short*)d_ws;                 // [B,T,64] bf16 (prescaled)
    unsigned short* kbf  = qbf + (size_t)MTOT * HS_;              // [B,T,64] bf16
    unsigned short* vtbf = kbf + (size_t)MTOT * HS_;              // [B,64,T] bf16
    unsigned short* Wt   = vtbf + (size_t)MTOT * HS_;             // [192][1024] bf16

    cast_w_kernel<<<dim3(32, 3), 256, 0, stream>>>(Wq, Wk, Wv, Wt);
    proj_gemm<<<dim3(MTOT / 64, 3), 256, 0, stream>>>(x, Wt, qbf, kbf, vtbf);
    attn_kernel<<<dim3(32, B_), 512, 0, stream>>>(qbf, kbf, vtbf, (float*)d_out);
}

// Round 6
// 50.097 us; speedup vs baseline: 5.7131x; 1.0144x over previous
//
#include <hip/hip_runtime.h>
#include <hip/hip_bf16.h>
#include <math.h>

#define B_   8
#define T_   2048
#define C_   1024
#define HS_  64
#define MTOT (B_*T_)          // 16384 rows

typedef __attribute__((ext_vector_type(8))) short bf16x8;           // MFMA A/B
typedef __attribute__((ext_vector_type(4))) float f32x4;            // MFMA C/D
typedef __attribute__((ext_vector_type(8))) unsigned short u16x8;   // 16B store

static __device__ __forceinline__ unsigned short f2bf(float f) {
    __hip_bfloat16 h = __float2bfloat16(f);
    return *reinterpret_cast<unsigned short*>(&h);
}

// ---------------------------------------------------------------------------
// Kernel 0: cast W -> bf16, TRANSPOSED + concatenated: Wt[n=192][k=1024].
// Q section pre-scaled by C^-0.5.  (validated r2-r4, unchanged)
// ---------------------------------------------------------------------------
__global__ __launch_bounds__(256) void cast_w_kernel(
    const float* __restrict__ Wq, const float* __restrict__ Wk,
    const float* __restrict__ Wv, unsigned short* __restrict__ Wt)
{
    const int tid = threadIdx.x;
    const int col = tid & 63;
    const int kc  = tid >> 6;                     // 0..3
    const int mat = blockIdx.y;
    const int k0  = (blockIdx.x * 4 + kc) * 8;
    const float* __restrict__ W = (mat == 0) ? Wq : (mat == 1) ? Wk : Wv;
    const float s = (mat == 0) ? 0.03125f : 1.0f;

    u16x8 o;
#pragma unroll
    for (int i = 0; i < 8; ++i)
        o[i] = f2bf(W[(size_t)(k0 + i) * HS_ + col] * s);
    *(u16x8*)&Wt[(size_t)(mat * 64 + col) * C_ + k0] = o;
}

// ---------------------------------------------------------------------------
// Kernel 1: FUSED QKV projection via bf16 MFMA.  grid = 256 blocks x 512 thr
// (8 waves).  Each block: 64 rows x 192 cols (all three mats) -> x staged
// once (was 3x).  Waves: wr = wv&1 (row half 32), cg = wv>>1 (48-col group,
// 3 frag-cols).  Double-buffered issue-early/write-late (validated r3).
// Fragment convention validated r1-r4 (unchanged).
// ---------------------------------------------------------------------------
__global__ __launch_bounds__(512) void proj_gemm(
    const float* __restrict__ x, const unsigned short* __restrict__ Wt,
    unsigned short* __restrict__ qbf, unsigned short* __restrict__ kbf,
    unsigned short* __restrict__ vtbf)
{
    __shared__ unsigned short Als[2][64][72];    // A tile [row][k]
    __shared__ unsigned short Bls[2][192][72];   // B tile [n=mat*64+col][k]

    const int tid  = threadIdx.x;
    const int lane = tid & 63;
    const int wv   = tid >> 6;        // 0..7
    const int wr   = wv & 1;          // row half (32)
    const int cg   = wv >> 1;         // col group: cols cg*48 .. +47
    const int g    = lane >> 4;
    const int n15  = lane & 15;
    const int g4   = g * 4;
    const int m0   = blockIdx.x * 64;

    // staging map: 8 threads per row, 8 elems each
    const int srow = tid >> 3;        // 0..63
    const int seg  = (tid & 7) * 8;
    const float* __restrict__ xrow = &x[(size_t)(m0 + srow) * C_ + seg];
    const unsigned short* __restrict__ wrow = &Wt[(size_t)srow * C_ + seg];

    f32x4 acc[2][3];
#pragma unroll
    for (int i = 0; i < 2; ++i)
#pragma unroll
        for (int j = 0; j < 3; ++j) acc[i][j] = (f32x4){0.f, 0.f, 0.f, 0.f};

    float4 a0, a1;
    int4   b0, b1, b2;

#define PROJ_LOAD(KC)                                                   \
    do {                                                                \
        a0 = *(const float4*)&xrow[(KC) * 64 + 0];                      \
        a1 = *(const float4*)&xrow[(KC) * 64 + 4];                      \
        b0 = *(const int4*)&wrow[(KC) * 64];                            \
        b1 = *(const int4*)&wrow[(size_t)64  * C_ + (KC) * 64];        \
        b2 = *(const int4*)&wrow[(size_t)128 * C_ + (KC) * 64];        \
    } while (0)

#define PROJ_WRITE(BUF)                                                 \
    do {                                                                \
        u16x8 v0;                                                       \
        v0[0]=f2bf(a0.x); v0[1]=f2bf(a0.y); v0[2]=f2bf(a0.z); v0[3]=f2bf(a0.w); \
        v0[4]=f2bf(a1.x); v0[5]=f2bf(a1.y); v0[6]=f2bf(a1.z); v0[7]=f2bf(a1.w); \
        *(u16x8*)&Als[BUF][srow][seg]       = v0;                       \
        *(int4*)&Bls[BUF][srow][seg]        = b0;                       \
        *(int4*)&Bls[BUF][srow + 64][seg]   = b1;                       \
        *(int4*)&Bls[BUF][srow + 128][seg]  = b2;                       \
    } while (0)

    PROJ_LOAD(0);
    PROJ_WRITE(0);
    __syncthreads();

    for (int kc = 0; kc < C_ / 64; ++kc) {
        const int cur = kc & 1;
        const int kn  = (kc + 1 < C_ / 64) ? kc + 1 : kc;   // clamped
        PROJ_LOAD(kn);                                      // issue early

#pragma unroll
        for (int kk = 0; kk < 2; ++kk) {
            bf16x8 fa0 = *(const bf16x8*)&Als[cur][wr * 32 + n15][kk * 32 + g * 8];
            bf16x8 fa1 = *(const bf16x8*)&Als[cur][wr * 32 + 16 + n15][kk * 32 + g * 8];
            bf16x8 fb0 = *(const bf16x8*)&Bls[cur][cg * 48 + n15][kk * 32 + g * 8];
            bf16x8 fb1 = *(const bf16x8*)&Bls[cur][cg * 48 + 16 + n15][kk * 32 + g * 8];
            bf16x8 fb2 = *(const bf16x8*)&Bls[cur][cg * 48 + 32 + n15][kk * 32 + g * 8];
            acc[0][0] = __builtin_amdgcn_mfma_f32_16x16x32_bf16(fa0, fb0, acc[0][0], 0, 0, 0);
            acc[0][1] = __builtin_amdgcn_mfma_f32_16x16x32_bf16(fa0, fb1, acc[0][1], 0, 0, 0);
            acc[0][2] = __builtin_amdgcn_mfma_f32_16x16x32_bf16(fa0, fb2, acc[0][2], 0, 0, 0);
            acc[1][0] = __builtin_amdgcn_mfma_f32_16x16x32_bf16(fa1, fb0, acc[1][0], 0, 0, 0);
            acc[1][1] = __builtin_amdgcn_mfma_f32_16x16x32_bf16(fa1, fb1, acc[1][1], 0, 0, 0);
            acc[1][2] = __builtin_amdgcn_mfma_f32_16x16x32_bf16(fa1, fb2, acc[1][2], 0, 0, 0);
        }

        if (kc + 1 < C_ / 64) {
            __syncthreads();            // everyone done reading buf cur^1
            PROJ_WRITE(cur ^ 1);        // write regs late (vmcnt waits land here)
            __syncthreads();            // tile kc+1 visible
        }
    }
#undef PROJ_LOAD
#undef PROJ_WRITE

    // ---- epilogue: stage C tile in LDS, then coalesced stores ----
    __syncthreads();                    // all MFMA reads done; LDS reusable
    unsigned short* Cqk = &Als[0][0][0];   // [64][136]  (8704 u16 <= 9216)
    unsigned short* Vtr = &Bls[0][0][0];   // [64(hs)][72] transposed v

#pragma unroll
    for (int i = 0; i < 2; ++i)
#pragma unroll
        for (int j = 0; j < 3; ++j) {
            const int gcol = cg * 48 + j * 16 + n15;
            const int row0 = wr * 32 + i * 16 + g4;
            if (gcol < 128) {           // q | k : row-major
#pragma unroll
                for (int r = 0; r < 4; ++r)
                    Cqk[(size_t)(row0 + r) * 136 + gcol] = f2bf(acc[i][j][r]);
            } else {                    // v : transposed [hs][tok]
                ushort4 o;
                o.x = f2bf(acc[i][j][0]); o.y = f2bf(acc[i][j][1]);
                o.z = f2bf(acc[i][j][2]); o.w = f2bf(acc[i][j][3]);
                *(ushort4*)&Vtr[(size_t)(gcol - 128) * 72 + row0] = o;
            }
        }
    __syncthreads();

    // q/k stores: 1024 int4-chunks over 2 mats
#pragma unroll
    for (int p = 0; p < 2; ++p) {
        const int flat = tid + p * 512;
        const int mat  = flat >> 9;          // 0=q, 1=k
        const int r64  = (flat >> 3) & 63;
        const int sg   = (flat & 7) * 8;
        unsigned short* __restrict__ dst = mat ? kbf : qbf;
        *(int4*)&dst[(size_t)(m0 + r64) * HS_ + sg] =
            *(const int4*)&Cqk[(size_t)r64 * 136 + mat * 64 + sg];
    }
    // v stores: [hs][tok] -> vt[b][hs][t0+tok]
    {
        const int b  = m0 >> 11;
        const int t0 = m0 & 2047;
        const int hs = tid >> 3;             // 0..63
        *(int4*)&vtbf[((size_t)b * HS_ + hs) * T_ + t0 + seg] =
            *(const int4*)&Vtr[(size_t)hs * 72 + seg];
    }
}

// ---------------------------------------------------------------------------
// Kernel 2: causal flash attention, bf16 MFMA, 8-wave tile-parity split-K
// (validated r4, unchanged).
// ---------------------------------------------------------------------------
__global__ __launch_bounds__(512) void attn_kernel(
    const unsigned short* __restrict__ qbf,
    const unsigned short* __restrict__ kbf,
    const unsigned short* __restrict__ vtbf,
    float* __restrict__ y)
{
    __shared__ unsigned short KVs[4][64][72];   // [0..1]=K bufs, [2..3]=V bufs

    const int tid  = threadIdx.x;
    const int lane = tid & 63;
    const int wv   = tid >> 6;        // 0..7
    const int rg   = wv & 1;          // query 16-group
    const int h    = (wv >> 1) & 1;   // KV 32-half within tile
    const int tp   = wv >> 2;         // tile parity group
    const int g    = lane >> 4;
    const int n15  = lane & 15;
    const int g4   = g * 4;
    const int b    = blockIdx.y;
    const size_t qkoff = (size_t)b * T_ * HS_;
    const size_t voff  = (size_t)b * HS_ * T_;

    const int sgrp = tid >> 8;        // staging group == its waves' tp
    const int st   = tid & 255;
    const int srow = st >> 3;         // 0..31
    const int soff = (st & 7) * 8;

    const unsigned short* __restrict__ kgb = &kbf[qkoff];
    const unsigned short* __restrict__ vgb = &vtbf[voff];

    for (int pass = 0; pass < 2; ++pass) {
        const int qbi  = pass ? (63 - (int)blockIdx.x) : (int)blockIdx.x;
        const int q0   = qbi * 32;
        const int qq0  = q0 + rg * 16;
        const int qrow = qq0 + n15;
        const int nkt  = (qbi >> 1) + 1;

        bf16x8 qf0 = *(const bf16x8*)&qbf[qkoff + (size_t)qrow * HS_ + g * 8];
        bf16x8 qf1 = *(const bf16x8*)&qbf[qkoff + (size_t)qrow * HS_ + g * 8 + 32];

        f32x4 o0 = {0.f,0.f,0.f,0.f}, o1 = o0, o2 = o0, o3 = o0;
        float mrow = -INFINITY, lrow = 0.f;

        int4 kr0, kr1, vr0, vr1;
        {
            int tix = (sgrp < nkt) ? sgrp : nkt - 1;
            kr0 = *(const int4*)&kgb[(size_t)(tix * 64 + srow) * HS_ + soff];
            kr1 = *(const int4*)&kgb[(size_t)(tix * 64 + srow + 32) * HS_ + soff];
            vr0 = *(const int4*)&vgb[(size_t)srow * T_ + tix * 64 + soff];
            vr1 = *(const int4*)&vgb[(size_t)(srow + 32) * T_ + tix * 64 + soff];
        }
        __syncthreads();                 // prior pass done with LDS
        *(int4*)&KVs[sgrp][srow][soff]          = kr0;
        *(int4*)&KVs[sgrp][srow + 32][soff]     = kr1;
        *(int4*)&KVs[2 + sgrp][srow][soff]      = vr0;
        *(int4*)&KVs[2 + sgrp][srow + 32][soff] = vr1;
        __syncthreads();

        const int J = (nkt + 1) >> 1;
        for (int j = 0; j < J; ++j) {
            const int kt = 2 * j + tp;                 // my compute tile
            {
                int tix = 2 * j + sgrp + 2;            // my group's next tile
                if (tix > nkt - 1) tix = nkt - 1;      // clamped
                kr0 = *(const int4*)&kgb[(size_t)(tix * 64 + srow) * HS_ + soff];
                kr1 = *(const int4*)&kgb[(size_t)(tix * 64 + srow + 32) * HS_ + soff];
                vr0 = *(const int4*)&vgb[(size_t)srow * T_ + tix * 64 + soff];
                vr1 = *(const int4*)&vgb[(size_t)(srow + 32) * T_ + tix * 64 + soff];
            }

            if (kt < nkt) {
                const int k0  = kt * 64;
                const int ks0 = h * 32;
                f32x4 st0 = {0.f,0.f,0.f,0.f}, st1 = st0;
                {
                    bf16x8 ka;
                    ka  = *(const bf16x8*)&KVs[tp][ks0 + n15][g * 8];
                    st0 = __builtin_amdgcn_mfma_f32_16x16x32_bf16(ka, qf0, st0, 0, 0, 0);
                    ka  = *(const bf16x8*)&KVs[tp][ks0 + n15][g * 8 + 32];
                    st0 = __builtin_amdgcn_mfma_f32_16x16x32_bf16(ka, qf1, st0, 0, 0, 0);
                    ka  = *(const bf16x8*)&KVs[tp][ks0 + 16 + n15][g * 8];
                    st1 = __builtin_amdgcn_mfma_f32_16x16x32_bf16(ka, qf0, st1, 0, 0, 0);
                    ka  = *(const bf16x8*)&KVs[tp][ks0 + 16 + n15][g * 8 + 32];
                    st1 = __builtin_amdgcn_mfma_f32_16x16x32_bf16(ka, qf1, st1, 0, 0, 0);
                }

                const int kb = k0 + h * 32 + g4;
#pragma unroll
                for (int r = 0; r < 4; ++r) {
                    if (kb + r      > qrow) st0[r] = -INFINITY;
                    if (kb + 16 + r > qrow) st1[r] = -INFINITY;
                }

                float mloc = fmaxf(fmaxf(st0[0], st0[1]), fmaxf(st0[2], st0[3]));
                mloc = fmaxf(mloc, fmaxf(fmaxf(st1[0], st1[1]), fmaxf(st1[2], st1[3])));
                mloc = fmaxf(mloc, __shfl_xor(mloc, 16));
                mloc = fmaxf(mloc, __shfl_xor(mloc, 32));
                float mnew = fmaxf(mrow, mloc);
                float mb   = fmaxf(mnew, -1e30f);
                float corr = __expf(mrow - mb);
                float p[8];
                float psum = 0.f;
#pragma unroll
                for (int r = 0; r < 4; ++r) {
                    p[r]     = __expf(st0[r] - mb);
                    p[4 + r] = __expf(st1[r] - mb);
                    psum += p[r] + p[4 + r];
                }
                psum += __shfl_xor(psum, 16);
                psum += __shfl_xor(psum, 32);
                lrow = lrow * corr + psum;
                mrow = mnew;

#pragma unroll
                for (int r = 0; r < 4; ++r) {
                    float cr = __shfl(corr, g4 + r);
                    o0[r] *= cr; o1[r] *= cr; o2[r] *= cr; o3[r] *= cr;
                }

                bf16x8 pa;
#pragma unroll
                for (int r = 0; r < 4; ++r) {
                    pa[r]     = (short)f2bf(p[r]);
                    pa[4 + r] = (short)f2bf(p[4 + r]);
                }

                const int kvo = h * 32;
                {
                    ushort4 lo, hi; bf16x8 vb;
#define PV_STEP(NT, ONT)                                                        \
                    lo = *(const ushort4*)&KVs[2 + tp][(NT)*16 + n15][kvo + g4];\
                    hi = *(const ushort4*)&KVs[2 + tp][(NT)*16 + n15][kvo + 16 + g4];\
                    vb[0] = (short)lo.x; vb[1] = (short)lo.y;                   \
                    vb[2] = (short)lo.z; vb[3] = (short)lo.w;                   \
                    vb[4] = (short)hi.x; vb[5] = (short)hi.y;                   \
                    vb[6] = (short)hi.z; vb[7] = (short)hi.w;                   \
                    ONT = __builtin_amdgcn_mfma_f32_16x16x32_bf16(pa, vb, ONT, 0, 0, 0);
                    PV_STEP(0, o0)
                    PV_STEP(1, o1)
                    PV_STEP(2, o2)
                    PV_STEP(3, o3)
#undef PV_STEP
                }
            }

            if (j + 1 < J) {
                __syncthreads();                 // all readers done with both bufs
                *(int4*)&KVs[sgrp][srow][soff]          = kr0;
                *(int4*)&KVs[sgrp][srow + 32][soff]     = kr1;
                *(int4*)&KVs[2 + sgrp][srow][soff]      = vr0;
                *(int4*)&KVs[2 + sgrp][srow + 32][soff] = vr1;
                __syncthreads();                 // next tiles visible
            }
        }

        // ---- 4-way merge (partials pid = tp*2+h) in reused LDS ----
        __syncthreads();                          // all compute done
        float* FS = (float*)&KVs[0][0][0];        // 9216 floats scratch
        const int pid = (tp << 1) | h;
        if (pid != 0) {
            float* Ob = FS + (pid - 1) * 2176 + rg * 1088;
#pragma unroll
            for (int r = 0; r < 4; ++r) {
                Ob[(g4 + r) * 68 +  0 + n15] = o0[r];
                Ob[(g4 + r) * 68 + 16 + n15] = o1[r];
                Ob[(g4 + r) * 68 + 32 + n15] = o2[r];
                Ob[(g4 + r) * 68 + 48 + n15] = o3[r];
            }
            if (g == 0) {
                FS[6528 + (pid - 1) * 32 + rg * 16 + n15] = mrow;
                FS[6624 + (pid - 1) * 32 + rg * 16 + n15] = lrow;
            }
        }
        __syncthreads();
        if (pid == 0) {
            float m1 = FS[6528 +  0 + rg * 16 + n15];
            float m2 = FS[6528 + 32 + rg * 16 + n15];
            float m3 = FS[6528 + 64 + rg * 16 + n15];
            float l1 = FS[6624 +  0 + rg * 16 + n15];
            float l2 = FS[6624 + 32 + rg * 16 + n15];
            float l3 = FS[6624 + 64 + rg * 16 + n15];
            float mm = fmaxf(fmaxf(mrow, m1), fmaxf(m2, m3));
            float f0 = __expf(mrow - mm);
            float f1 = __expf(m1 - mm);
            float f2 = __expf(m2 - mm);
            float f3 = __expf(m3 - mm);
            float invl = 1.0f / (lrow * f0 + l1 * f1 + l2 * f2 + l3 * f3);
            const float* O1s = FS;
            const float* O2s = FS + 2176;
            const float* O3s = FS + 4352;
#pragma unroll
            for (int r = 0; r < 4; ++r) {
                float fr0 = __shfl(f0, g4 + r);
                float fr1 = __shfl(f1, g4 + r);
                float fr2 = __shfl(f2, g4 + r);
                float fr3 = __shfl(f3, g4 + r);
                float ir  = __shfl(invl, g4 + r);
                const int base = rg * 1088 + (g4 + r) * 68 + n15;
                float* yr = &y[((size_t)b * T_ + qq0 + g4 + r) * HS_];
                yr[ 0 + n15] = (o0[r] * fr0 + O1s[base]      * fr1 +
                                O2s[base]      * fr2 + O3s[base]      * fr3) * ir;
                yr[16 + n15] = (o1[r] * fr0 + O1s[base + 16] * fr1 +
                                O2s[base + 16] * fr2 + O3s[base + 16] * fr3) * ir;
                yr[32 + n15] = (o2[r] * fr0 + O1s[base + 32] * fr1 +
                                O2s[base + 32] * fr2 + O3s[base + 32] * fr3) * ir;
                yr[48 + n15] = (o3[r] * fr0 + O1s[base + 48] * fr1 +
                                O2s[base + 48] * fr2 + O3s[base + 48] * fr3) * ir;
            }
        }
    }
}

extern "C" void kernel_launch(void* const* d_in, const int* in_sizes, int n_in,
                              void* d_out, int out_size, void* d_ws, size_t ws_size,
                              hipStream_t stream)
{
    const float* x  = (const float*)d_in[0];
    const float* Wq = (const float*)d_in[1];
    const float* Wk = (const float*)d_in[2];
    const float* Wv = (const float*)d_in[3];

    unsigned short* qbf  = (unsigned short*)d_ws;                 // [B,T,64] bf16 (prescaled)
    unsigned short* kbf  = qbf + (size_t)MTOT * HS_;              // [B,T,64] bf16
    unsigned short* vtbf = kbf + (size_t)MTOT * HS_;              // [B,64,T] bf16
    unsigned short* Wt   = vtbf + (size_t)MTOT * HS_;             // [192][1024] bf16

    cast_w_kernel<<<dim3(32, 3), 256, 0, stream>>>(Wq, Wk, Wv, Wt);
    proj_gemm<<<256, 512, 0, stream>>>(x, Wt, qbf, kbf, vtbf);
    attn_kernel<<<dim3(32, B_), 512, 0, stream>>>(qbf, kbf, vtbf, (float*)d_out);
}